// Round 5
// baseline (2404.355 us; speedup 1.0000x reference)
//
#include <hip/hip_runtime.h>
#include <math.h>

// BiLSTM-CRF fp32, round 5.
// k_step v3: NO LDS / NO barriers in the GEMM. A (x|h rows) = wave-uniform
// broadcast loads; B (W columns) = per-lane loads (L2/XCD-resident via swizzle).
// k_viterbi v2: pipelined-shuffle + tournament-tree forward, speculative
// segmented backtrack.
// ws layout (floats): x[16384*256] | hs_f[32*512*256] | hs_b[32*512*256] |
//                     c_f[512*256] | c_b[512*256] | feats[16384*11]   (~52 MiB)
// Output: d_out[0:32]=score(f32), d_out[32:32+16384]=path (float-encoded ints).

namespace {

constexpr int E_ = 256;    // embed dim
constexpr int H_ = 256;    // hidden per dir
constexpr int T_ = 11;     // tags

// ---------------- K1: embedding gather ----------------
__global__ __launch_bounds__(256) void k_gather(const int* __restrict__ sent,
                                                const float* __restrict__ embed,
                                                float* __restrict__ x) {
  int i = blockIdx.x * 256 + threadIdx.x;   // float4 id over 16384*64
  int row = i >> 6;
  int e = (i & 63) << 2;
  int tok = sent[row];
  *(float4*)(x + (size_t)row * E_ + e) =
      *(const float4*)(embed + (size_t)tok * E_ + e);
}

// ---------------- K2: one fused LSTM step, K=512, LDS-free GEMM ----------------
// 512 blocks x 256 thr = 2048 independent waves. Wave: 8 s-rows x 64 gate-cols
// (lane: q=lane>>4 in {i,f,g,o}, jl=lane&15). acc[8]. Epilogue via small Cs LDS.
__global__ __launch_bounds__(256) void k_step(
    const float* __restrict__ x,
    const float* __restrict__ w_ih_f, const float* __restrict__ w_hh_f,
    const float* __restrict__ b_ih_f, const float* __restrict__ b_hh_f,
    const float* __restrict__ w_ih_b, const float* __restrict__ w_hh_b,
    const float* __restrict__ b_ih_b, const float* __restrict__ b_hh_b,
    const float* __restrict__ h0, const float* __restrict__ c0,
    float* __restrict__ hs_f, float* __restrict__ hs_b,
    float* __restrict__ c_f, float* __restrict__ c_b, int t) {
  __shared__ float Cs[32][65];                 // gates round-trip (epilogue only)
  const int tid = threadIdx.x;
  // XCD-ownership swizzle: xcd owns 4 colgroups; W slice/XCD = 512KB, L2-resident
  const int gid = blockIdx.x;            // 0..511
  const int xcd = gid & 7, slot = gid >> 3;    // slot 0..63
  const int cg = xcd * 4 + (slot >> 4);        // colgroup 0..31 = (d, cb)
  const int bic = slot & 15;                   // block-in-colgroup: rows bic*32..+32
  const int d = cg >> 4, cb = cg & 15;

  const int wid = __builtin_amdgcn_readfirstlane(tid >> 6);
  const int lane = tid & 63;
  const int s0 = bic * 32;                     // block row base
  const int r0 = s0 + wid * 8;                 // wave row base (8 rows)
  const int q = lane >> 4, jl = lane & 15;
  const int j = cb * 16 + jl;                  // hidden col 0..255
  const int gc = q * 256 + j;                  // gate col 0..1023

  const float* wih = d ? w_ih_b : w_ih_f;
  const float* whh = d ? w_hh_b : w_hh_f;
  const int tt = d ? 31 - t : t;
  const float* xs = x + (size_t)tt * 512 * E_;
  const float* hprev = (t == 0) ? h0 + (size_t)d * 512 * H_
                      : (d ? hs_b + (size_t)(32 - t) * 512 * H_
                           : hs_f + (size_t)(t - 1) * 512 * H_);
  float* hout = d ? hs_b + (size_t)(31 - t) * 512 * H_
                  : hs_f + (size_t)t * 512 * H_;
  float* cbuf = d ? c_b : c_f;
  const float* cprev = (t == 0) ? c0 + (size_t)d * 512 * H_ : cbuf;

  const float* browi = wih + (size_t)gc * E_;  // lane's W_ih row
  const float* browh = whh + (size_t)gc * H_;  // lane's W_hh row

  float acc[8];
#pragma unroll
  for (int r = 0; r < 8; ++r) acc[r] = 0.f;

#pragma unroll 1
  for (int ph = 0; ph < 2; ++ph) {
    const float* ap = ph ? hprev + (size_t)r0 * H_ : xs + (size_t)r0 * E_;
    const float* bp = ph ? browh : browi;
#pragma unroll 2
    for (int kk = 0; kk < 256; kk += 16) {
      float4 b0 = *(const float4*)(bp + kk);
      float4 b1 = *(const float4*)(bp + kk + 4);
      float4 b2 = *(const float4*)(bp + kk + 8);
      float4 b3 = *(const float4*)(bp + kk + 12);
#pragma unroll
      for (int r = 0; r < 8; ++r) {
        const float* ar = ap + (size_t)r * 256 + kk;   // wave-uniform address
        float4 a0 = *(const float4*)(ar);
        float4 a1 = *(const float4*)(ar + 4);
        float4 a2 = *(const float4*)(ar + 8);
        float4 a3 = *(const float4*)(ar + 12);
        float s = acc[r];
        s = fmaf(a0.x, b0.x, s); s = fmaf(a0.y, b0.y, s);
        s = fmaf(a0.z, b0.z, s); s = fmaf(a0.w, b0.w, s);
        s = fmaf(a1.x, b1.x, s); s = fmaf(a1.y, b1.y, s);
        s = fmaf(a1.z, b1.z, s); s = fmaf(a1.w, b1.w, s);
        s = fmaf(a2.x, b2.x, s); s = fmaf(a2.y, b2.y, s);
        s = fmaf(a2.z, b2.z, s); s = fmaf(a2.w, b2.w, s);
        s = fmaf(a3.x, b3.x, s); s = fmaf(a3.y, b3.y, s);
        s = fmaf(a3.z, b3.z, s); s = fmaf(a3.w, b3.w, s);
        acc[r] = s;
      }
    }
  }

  // epilogue: gather 4 gate quadrants per cell via LDS
#pragma unroll
  for (int r = 0; r < 8; ++r) Cs[wid * 8 + r][lane] = acc[r];
  __syncthreads();

  const float* bi = d ? b_ih_b : b_ih_f;
  const float* bh = d ? b_hh_b : b_hh_f;
#pragma unroll
  for (int u = 0; u < 2; ++u) {
    int idx = tid + 256 * u;
    int sl = idx >> 4, jj = idx & 15;
    int s = s0 + sl, jc = cb * 16 + jj;
    float gi = Cs[sl][jj]      + bi[jc]       + bh[jc];
    float gf = Cs[sl][16 + jj] + bi[256 + jc] + bh[256 + jc];
    float gg = Cs[sl][32 + jj] + bi[512 + jc] + bh[512 + jc];
    float go = Cs[sl][48 + jj] + bi[768 + jc] + bh[768 + jc];
    float si = 1.f / (1.f + expf(-gi));
    float sf = 1.f / (1.f + expf(-gf));
    float tg = tanhf(gg);
    float so = 1.f / (1.f + expf(-go));
    float cp = cprev[(size_t)s * H_ + jc];
    float cn = sf * cp + si * tg;
    float hn = so * tanhf(cn);
    cbuf[(size_t)s * H_ + jc] = cn;
    hout[(size_t)s * H_ + jc] = hn;
  }
}

// ---------------- K3: feats = [hs_f|hs_b] @ w_out.T + b_out ----------------
__global__ __launch_bounds__(256) void k_out_gemm(
    const float* __restrict__ hs_f, const float* __restrict__ hs_b,
    const float* __restrict__ w_out, const float* __restrict__ b_out,
    float* __restrict__ feats) {
  __shared__ __align__(16) float wl[T_ * 512];
  for (int i = threadIdx.x; i < T_ * 512; i += 256) wl[i] = w_out[i];
  __syncthreads();
  int wave = threadIdx.x >> 6, lane = threadIdx.x & 63;
  size_t row = (size_t)blockIdx.x * 4 + wave;   // 0..16383
  float4 hf = *(const float4*)(hs_f + row * H_ + lane * 4);
  float4 hb = *(const float4*)(hs_b + row * H_ + lane * 4);
#pragma unroll
  for (int tag = 0; tag < T_; ++tag) {
    float4 wf = *(const float4*)&wl[tag * 512 + lane * 4];
    float4 wb = *(const float4*)&wl[tag * 512 + 256 + lane * 4];
    float p = hf.x * wf.x + hf.y * wf.y + hf.z * wf.z + hf.w * wf.w +
              hb.x * wb.x + hb.y * wb.y + hb.z * wb.z + hb.w * wb.w;
#pragma unroll
    for (int off = 32; off; off >>= 1) p += __shfl_xor(p, off, 64);
    if (lane == 0) feats[row * T_ + tag] = p + b_out[tag];
  }
}

// ---------------- K4: Viterbi, 1 block (128 thr) per batch elem ----------------
// Forward on wave 0: 11 pipelined shuffles + depth-4 >=-left tournament tree
// (first-max ties == jnp.argmax). Backtrack: speculative segmented (121 lanes).
#define PAIR(va, ia, vb, ib, vo, io) { bool c_ = (va) >= (vb); vo = c_ ? (va) : (vb); io = c_ ? (ia) : (ib); }

__global__ __launch_bounds__(128) void k_viterbi(const float* __restrict__ feats,
                                                 const float* __restrict__ trans,
                                                 float* __restrict__ out) {
  __shared__ float fl[512 * T_];              // 22.5 KB
  __shared__ unsigned char psiL[511 * T_];    // 5.6 KB
  __shared__ unsigned char specL[121 * 47];   // 5.7 KB
  __shared__ unsigned char selL[16];
  __shared__ int lastL;
  __shared__ float scoreL;
  const int b = blockIdx.x, tid = threadIdx.x;
  const float* fb = feats + (size_t)b * 512 * T_;
  for (int i = tid; i < 512 * T_; i += 128) fl[i] = fb[i];
  __syncthreads();

  if (tid < 64) {   // wave 0: forward recursion
    const int lane = tid;
    const int to = (lane < T_) ? lane : 0;
    float tr[T_];
#pragma unroll
    for (int f = 0; f < T_; ++f) tr[f] = trans[to * T_ + f];
    float delta = (lane == 9) ? 0.f : -10000.f;   // START=9

    for (int s = 1; s < 512; ++s) {
      float v0 = tr[0] + __shfl(delta, 0, 64);
      float v1 = tr[1] + __shfl(delta, 1, 64);
      float v2 = tr[2] + __shfl(delta, 2, 64);
      float v3 = tr[3] + __shfl(delta, 3, 64);
      float v4 = tr[4] + __shfl(delta, 4, 64);
      float v5 = tr[5] + __shfl(delta, 5, 64);
      float v6 = tr[6] + __shfl(delta, 6, 64);
      float v7 = tr[7] + __shfl(delta, 7, 64);
      float v8 = tr[8] + __shfl(delta, 8, 64);
      float v9 = tr[9] + __shfl(delta, 9, 64);
      float v10 = tr[10] + __shfl(delta, 10, 64);
      float mA, mB, mC, mD, mE, mG, mH, mI, mJ, m;
      int iA, iB, iC, iD, iE, iG, iH, iI, iJ, am;
      PAIR(v0, 0, v1, 1, mA, iA); PAIR(v2, 2, v3, 3, mB, iB);
      PAIR(v4, 4, v5, 5, mC, iC); PAIR(v6, 6, v7, 7, mD, iD);
      PAIR(v8, 8, v9, 9, mE, iE);
      PAIR(mA, iA, mB, iB, mG, iG); PAIR(mC, iC, mD, iD, mH, iH);
      PAIR(mE, iE, v10, 10, mI, iI);
      PAIR(mG, iG, mH, iH, mJ, iJ);
      PAIR(mJ, iJ, mI, iI, m, am);
      if (lane < T_) psiL[(s - 1) * T_ + lane] = (unsigned char)am;
      delta = m + fl[s * T_ + to];
    }
    // score + last tag (uniform on all lanes of wave 0)
    float d0 = __shfl(delta, 0, 64), d1 = __shfl(delta, 1, 64);
    float d2 = __shfl(delta, 2, 64), d3 = __shfl(delta, 3, 64);
    float d4 = __shfl(delta, 4, 64), d5 = __shfl(delta, 5, 64);
    float d6 = __shfl(delta, 6, 64), d7 = __shfl(delta, 7, 64);
    float d8 = __shfl(delta, 8, 64), d9 = __shfl(delta, 9, 64);
    float d10 = __shfl(delta, 10, 64);
    float mA, mB, mC, mD, mE, mG, mH, mI, mJ, m;
    int iA, iB, iC, iD, iE, iG, iH, iI, iJ, am;
    PAIR(d0, 0, d1, 1, mA, iA); PAIR(d2, 2, d3, 3, mB, iB);
    PAIR(d4, 4, d5, 5, mC, iC); PAIR(d6, 6, d7, 7, mD, iD);
    PAIR(d8, 8, d9, 9, mE, iE);
    PAIR(mA, iA, mB, iB, mG, iG); PAIR(mC, iC, mD, iD, mH, iH);
    PAIR(mE, iE, d10, 10, mI, iI);
    PAIR(mG, iG, mH, iH, mJ, iJ);
    PAIR(mJ, iJ, mI, iI, m, am);
    if (lane == 0) { lastL = am; scoreL = m; }
  }
  __syncthreads();

  // speculative segmented backtrack: seg g in [0,11), assumed entry tag tau
  const int last = lastL;
  if (tid < 121) {
    const int g = tid / 11, tau = tid - g * 11;
    const int khi = 510 - 47 * g;
    const int len = (g < 10) ? 47 : 41;
    int cur = tau;
    unsigned char* sp = &specL[(g * 11 + tau) * 47];
    for (int i = 0; i < len; ++i) {
      cur = psiL[(khi - i) * T_ + cur];
      sp[i] = (unsigned char)cur;
    }
  }
  __syncthreads();
  if (tid == 0) {
    int cur = last;
    for (int g = 0; g < 11; ++g) {
      selL[g] = (unsigned char)cur;
      int len = (g < 10) ? 47 : 41;
      cur = specL[(g * 11 + cur) * 47 + (len - 1)];
    }
    out[b] = scoreL;
    out[32 + (size_t)b * 512 + 511] = (float)last;
  }
  __syncthreads();
  if (tid < 121) {
    const int g = tid / 11, tau = tid - g * 11;
    if (tau == selL[g]) {
      const int khi = 510 - 47 * g;
      const int len = (g < 10) ? 47 : 41;
      float* path = out + 32 + (size_t)b * 512;
      const unsigned char* sp = &specL[(g * 11 + tau) * 47];
      for (int i = 0; i < len; ++i) path[khi - i] = (float)sp[i];
    }
  }
}

}  // namespace

extern "C" void kernel_launch(void* const* d_in, const int* in_sizes, int n_in,
                              void* d_out, int out_size, void* d_ws, size_t ws_size,
                              hipStream_t stream) {
  const int* sent     = (const int*)d_in[0];
  const float* embed  = (const float*)d_in[1];
  const float* w_ih_f = (const float*)d_in[2];
  const float* w_hh_f = (const float*)d_in[3];
  const float* b_ih_f = (const float*)d_in[4];
  const float* b_hh_f = (const float*)d_in[5];
  const float* w_ih_b = (const float*)d_in[6];
  const float* w_hh_b = (const float*)d_in[7];
  const float* b_ih_b = (const float*)d_in[8];
  const float* b_hh_b = (const float*)d_in[9];
  const float* h0     = (const float*)d_in[10];
  const float* c0     = (const float*)d_in[11];
  const float* w_out  = (const float*)d_in[12];
  const float* b_out  = (const float*)d_in[13];
  const float* trans  = (const float*)d_in[14];

  float* ws    = (float*)d_ws;
  float* x     = ws;                 // 16384*256 = 4,194,304
  float* hs_f  = x + 4194304;        // 32*512*256 = 4,194,304
  float* hs_b  = hs_f + 4194304;     // 4,194,304
  float* c_f   = hs_b + 4194304;     // 131,072
  float* c_b   = c_f + 131072;       // 131,072
  float* feats = c_b + 131072;       // 180,224
  // total ~12.9M floats = ~52 MiB of ws

  k_gather<<<4096, 256, 0, stream>>>(sent, embed, x);
  for (int t = 0; t < 32; ++t)
    k_step<<<512, 256, 0, stream>>>(
        x, w_ih_f, w_hh_f, b_ih_f, b_hh_f, w_ih_b, w_hh_b, b_ih_b, b_hh_b,
        h0, c0, hs_f, hs_b, c_f, c_b, t);
  k_out_gemm<<<4096, 256, 0, stream>>>(hs_f, hs_b, w_out, b_out, feats);
  k_viterbi<<<32, 128, 0, stream>>>(feats, trans, (float*)d_out);
}

// Round 6
// 1729.730 us; speedup vs baseline: 1.3900x; 1.3900x over previous
//
#include <hip/hip_runtime.h>
#include <math.h>

// BiLSTM-CRF fp32, round 6.
// k_step v5: A (x|h rows) via wave-uniform loads (scalar-cache path, no LDS);
// B (W panel) staged row-major into LDS [col][k] (no transpose), read as b64
// pairs -> ~0.5 B/FMA from LDS (under the 1 B/FMA LDS budget).
// k_viterbi v2 (111us) kept.
// ws layout (floats): x[16384*256] | hs_f[32*512*256] | hs_b[32*512*256] |
//                     c_f[512*256] | c_b[512*256] | feats[16384*11]   (~52 MiB)
// Output: d_out[0:32]=score(f32), d_out[32:32+16384]=path (float-encoded ints).

namespace {

constexpr int E_ = 256;    // embed dim
constexpr int H_ = 256;    // hidden per dir
constexpr int T_ = 11;     // tags

// ---------------- K1: embedding gather ----------------
__global__ __launch_bounds__(256) void k_gather(const int* __restrict__ sent,
                                                const float* __restrict__ embed,
                                                float* __restrict__ x) {
  int i = blockIdx.x * 256 + threadIdx.x;   // float4 id over 16384*64
  int row = i >> 6;
  int e = (i & 63) << 2;
  int tok = sent[row];
  *(float4*)(x + (size_t)row * E_ + e) =
      *(const float4*)(embed + (size_t)tok * E_ + e);
}

// ---------------- K2: fused LSTM step, K=512 ([x_t | h_prev]) ----------------
// 512 blocks x 256 thr. Block tile: 32 s x 64 gate-cols (lane -> col, wave ->
// 8 s-rows). A: wave-uniform global loads (scalar path). B: LDS [col][66].
__global__ __launch_bounds__(256) void k_step(
    const float* __restrict__ x,
    const float* __restrict__ w_ih_f, const float* __restrict__ w_hh_f,
    const float* __restrict__ b_ih_f, const float* __restrict__ b_hh_f,
    const float* __restrict__ w_ih_b, const float* __restrict__ w_hh_b,
    const float* __restrict__ b_ih_b, const float* __restrict__ b_hh_b,
    const float* __restrict__ h0, const float* __restrict__ c0,
    float* __restrict__ hs_f, float* __restrict__ hs_b,
    float* __restrict__ c_f, float* __restrict__ c_b, int t) {
  __shared__ float Bs[64][66];                 // [col][k], 16.9 KiB
  __shared__ float Cs[32][65];                 // gates round-trip, 8.3 KiB
  const int tid = threadIdx.x;
  // XCD-ownership swizzle: xcd owns 4 colgroups; W slice/XCD = 512KB (L2-res)
  const int gid = blockIdx.x;                  // 0..511
  const int xcd = gid & 7, slot = gid >> 3;    // slot 0..63
  const int cg = xcd * 4 + (slot >> 4);        // colgroup 0..31 = (d, cb)
  const int bic = slot & 15;                   // rows bic*32..+32
  const int d = cg >> 4, cb = cg & 15;

  const int wid = __builtin_amdgcn_readfirstlane(tid >> 6);
  const int lane = tid & 63;
  const int s0 = bic * 32;
  const int r0 = s0 + wid * 8;                 // wave's 8 s-rows

  const float* wih = d ? w_ih_b : w_ih_f;
  const float* whh = d ? w_hh_b : w_hh_f;
  const int tt = d ? 31 - t : t;
  const float* xs = x + (size_t)tt * 512 * E_;
  const float* hprev = (t == 0) ? h0 + (size_t)d * 512 * H_
                      : (d ? hs_b + (size_t)(32 - t) * 512 * H_
                           : hs_f + (size_t)(t - 1) * 512 * H_);
  float* hout = d ? hs_b + (size_t)(31 - t) * 512 * H_
                  : hs_f + (size_t)t * 512 * H_;
  float* cbuf = d ? c_b : c_f;
  const float* cprev = (t == 0) ? c0 + (size_t)d * 512 * H_ : cbuf;

  // staging ids: thread -> (col 0..63, k-slot 0..3); W rows are contiguous in
  // k, Bs is [col][k] -> straight copy, no transpose.
  const int scol = tid >> 2, sks = tid & 3;
  const int sgc = (scol >> 4) * 256 + cb * 16 + (scol & 15);
  const float* srowi = wih + (size_t)sgc * E_;
  const float* srowh = whh + (size_t)sgc * H_;

  float acc[8];
#pragma unroll
  for (int r = 0; r < 8; ++r) acc[r] = 0.f;

#pragma unroll 1
  for (int ph = 0; ph < 2; ++ph) {
    const float* ap = ph ? hprev + (size_t)r0 * H_ : xs + (size_t)r0 * E_;
    const float* bp0 = ph ? srowh : srowi;
#pragma unroll 1
    for (int ci = 0; ci < 4; ++ci) {
      const int k0 = ci * 64;
      const float* bp = bp0 + k0 + sks * 16;
      float4 g0 = *(const float4*)(bp + 0);
      float4 g1 = *(const float4*)(bp + 4);
      float4 g2 = *(const float4*)(bp + 8);
      float4 g3 = *(const float4*)(bp + 12);
      float* bsr = &Bs[scol][sks * 16];
      *(float2*)(bsr + 0)  = make_float2(g0.x, g0.y);
      *(float2*)(bsr + 2)  = make_float2(g0.z, g0.w);
      *(float2*)(bsr + 4)  = make_float2(g1.x, g1.y);
      *(float2*)(bsr + 6)  = make_float2(g1.z, g1.w);
      *(float2*)(bsr + 8)  = make_float2(g2.x, g2.y);
      *(float2*)(bsr + 10) = make_float2(g2.z, g2.w);
      *(float2*)(bsr + 12) = make_float2(g3.x, g3.y);
      *(float2*)(bsr + 14) = make_float2(g3.z, g3.w);
      __syncthreads();
#pragma unroll
      for (int kq = 0; kq < 16; ++kq) {
        float2 b0 = *(const float2*)&Bs[lane][kq * 4];
        float2 b1 = *(const float2*)&Bs[lane][kq * 4 + 2];
#pragma unroll
        for (int r = 0; r < 8; ++r) {
          // wave-uniform address -> scalar load (A never touches LDS/VMEM-vec)
          float4 a = *(const float4*)(ap + r * 256 + k0 + kq * 4);
          float s = acc[r];
          s = fmaf(a.x, b0.x, s);
          s = fmaf(a.y, b0.y, s);
          s = fmaf(a.z, b1.x, s);
          s = fmaf(a.w, b1.y, s);
          acc[r] = s;
        }
      }
      __syncthreads();
    }
  }

  // epilogue: gather 4 gate quadrants per cell via LDS
#pragma unroll
  for (int r = 0; r < 8; ++r) Cs[wid * 8 + r][lane] = acc[r];
  __syncthreads();

  const float* bi = d ? b_ih_b : b_ih_f;
  const float* bh = d ? b_hh_b : b_hh_f;
#pragma unroll
  for (int u = 0; u < 2; ++u) {
    int idx = tid + 256 * u;
    int sl = idx >> 4, jj = idx & 15;
    int s = s0 + sl, jc = cb * 16 + jj;
    float gi = Cs[sl][jj]      + bi[jc]       + bh[jc];
    float gf = Cs[sl][16 + jj] + bi[256 + jc] + bh[256 + jc];
    float gg = Cs[sl][32 + jj] + bi[512 + jc] + bh[512 + jc];
    float go = Cs[sl][48 + jj] + bi[768 + jc] + bh[768 + jc];
    float si = 1.f / (1.f + expf(-gi));
    float sf = 1.f / (1.f + expf(-gf));
    float tg = tanhf(gg);
    float so = 1.f / (1.f + expf(-go));
    float cp = cprev[(size_t)s * H_ + jc];
    float cn = sf * cp + si * tg;
    float hn = so * tanhf(cn);
    cbuf[(size_t)s * H_ + jc] = cn;
    hout[(size_t)s * H_ + jc] = hn;
  }
}

// ---------------- K3: feats = [hs_f|hs_b] @ w_out.T + b_out ----------------
__global__ __launch_bounds__(256) void k_out_gemm(
    const float* __restrict__ hs_f, const float* __restrict__ hs_b,
    const float* __restrict__ w_out, const float* __restrict__ b_out,
    float* __restrict__ feats) {
  __shared__ __align__(16) float wl[T_ * 512];
  for (int i = threadIdx.x; i < T_ * 512; i += 256) wl[i] = w_out[i];
  __syncthreads();
  int wave = threadIdx.x >> 6, lane = threadIdx.x & 63;
  size_t row = (size_t)blockIdx.x * 4 + wave;   // 0..16383
  float4 hf = *(const float4*)(hs_f + row * H_ + lane * 4);
  float4 hb = *(const float4*)(hs_b + row * H_ + lane * 4);
#pragma unroll
  for (int tag = 0; tag < T_; ++tag) {
    float4 wf = *(const float4*)&wl[tag * 512 + lane * 4];
    float4 wb = *(const float4*)&wl[tag * 512 + 256 + lane * 4];
    float p = hf.x * wf.x + hf.y * wf.y + hf.z * wf.z + hf.w * wf.w +
              hb.x * wb.x + hb.y * wb.y + hb.z * wb.z + hb.w * wb.w;
#pragma unroll
    for (int off = 32; off; off >>= 1) p += __shfl_xor(p, off, 64);
    if (lane == 0) feats[row * T_ + tag] = p + b_out[tag];
  }
}

// ---------------- K4: Viterbi, 1 block (128 thr) per batch elem ----------------
#define PAIR(va, ia, vb, ib, vo, io) { bool c_ = (va) >= (vb); vo = c_ ? (va) : (vb); io = c_ ? (ia) : (ib); }

__global__ __launch_bounds__(128) void k_viterbi(const float* __restrict__ feats,
                                                 const float* __restrict__ trans,
                                                 float* __restrict__ out) {
  __shared__ float fl[512 * T_];              // 22.5 KB
  __shared__ unsigned char psiL[511 * T_];    // 5.6 KB
  __shared__ unsigned char specL[121 * 47];   // 5.7 KB
  __shared__ unsigned char selL[16];
  __shared__ int lastL;
  __shared__ float scoreL;
  const int b = blockIdx.x, tid = threadIdx.x;
  const float* fb = feats + (size_t)b * 512 * T_;
  for (int i = tid; i < 512 * T_; i += 128) fl[i] = fb[i];
  __syncthreads();

  if (tid < 64) {   // wave 0: forward recursion
    const int lane = tid;
    const int to = (lane < T_) ? lane : 0;
    float tr[T_];
#pragma unroll
    for (int f = 0; f < T_; ++f) tr[f] = trans[to * T_ + f];
    float delta = (lane == 9) ? 0.f : -10000.f;   // START=9

    for (int s = 1; s < 512; ++s) {
      float v0 = tr[0] + __shfl(delta, 0, 64);
      float v1 = tr[1] + __shfl(delta, 1, 64);
      float v2 = tr[2] + __shfl(delta, 2, 64);
      float v3 = tr[3] + __shfl(delta, 3, 64);
      float v4 = tr[4] + __shfl(delta, 4, 64);
      float v5 = tr[5] + __shfl(delta, 5, 64);
      float v6 = tr[6] + __shfl(delta, 6, 64);
      float v7 = tr[7] + __shfl(delta, 7, 64);
      float v8 = tr[8] + __shfl(delta, 8, 64);
      float v9 = tr[9] + __shfl(delta, 9, 64);
      float v10 = tr[10] + __shfl(delta, 10, 64);
      float mA, mB, mC, mD, mE, mG, mH, mI, mJ, m;
      int iA, iB, iC, iD, iE, iG, iH, iI, iJ, am;
      PAIR(v0, 0, v1, 1, mA, iA); PAIR(v2, 2, v3, 3, mB, iB);
      PAIR(v4, 4, v5, 5, mC, iC); PAIR(v6, 6, v7, 7, mD, iD);
      PAIR(v8, 8, v9, 9, mE, iE);
      PAIR(mA, iA, mB, iB, mG, iG); PAIR(mC, iC, mD, iD, mH, iH);
      PAIR(mE, iE, v10, 10, mI, iI);
      PAIR(mG, iG, mH, iH, mJ, iJ);
      PAIR(mJ, iJ, mI, iI, m, am);
      if (lane < T_) psiL[(s - 1) * T_ + lane] = (unsigned char)am;
      delta = m + fl[s * T_ + to];
    }
    float d0 = __shfl(delta, 0, 64), d1 = __shfl(delta, 1, 64);
    float d2 = __shfl(delta, 2, 64), d3 = __shfl(delta, 3, 64);
    float d4 = __shfl(delta, 4, 64), d5 = __shfl(delta, 5, 64);
    float d6 = __shfl(delta, 6, 64), d7 = __shfl(delta, 7, 64);
    float d8 = __shfl(delta, 8, 64), d9 = __shfl(delta, 9, 64);
    float d10 = __shfl(delta, 10, 64);
    float mA, mB, mC, mD, mE, mG, mH, mI, mJ, m;
    int iA, iB, iC, iD, iE, iG, iH, iI, iJ, am;
    PAIR(d0, 0, d1, 1, mA, iA); PAIR(d2, 2, d3, 3, mB, iB);
    PAIR(d4, 4, d5, 5, mC, iC); PAIR(d6, 6, d7, 7, mD, iD);
    PAIR(d8, 8, d9, 9, mE, iE);
    PAIR(mA, iA, mB, iB, mG, iG); PAIR(mC, iC, mD, iD, mH, iH);
    PAIR(mE, iE, d10, 10, mI, iI);
    PAIR(mG, iG, mH, iH, mJ, iJ);
    PAIR(mJ, iJ, mI, iI, m, am);
    if (lane == 0) { lastL = am; scoreL = m; }
  }
  __syncthreads();

  // speculative segmented backtrack: seg g in [0,11), assumed entry tag tau
  const int last = lastL;
  if (tid < 121) {
    const int g = tid / 11, tau = tid - g * 11;
    const int khi = 510 - 47 * g;
    const int len = (g < 10) ? 47 : 41;
    int cur = tau;
    unsigned char* sp = &specL[(g * 11 + tau) * 47];
    for (int i = 0; i < len; ++i) {
      cur = psiL[(khi - i) * T_ + cur];
      sp[i] = (unsigned char)cur;
    }
  }
  __syncthreads();
  if (tid == 0) {
    int cur = last;
    for (int g = 0; g < 11; ++g) {
      selL[g] = (unsigned char)cur;
      int len = (g < 10) ? 47 : 41;
      cur = specL[(g * 11 + cur) * 47 + (len - 1)];
    }
    out[b] = scoreL;
    out[32 + (size_t)b * 512 + 511] = (float)last;
  }
  __syncthreads();
  if (tid < 121) {
    const int g = tid / 11, tau = tid - g * 11;
    if (tau == selL[g]) {
      const int khi = 510 - 47 * g;
      const int len = (g < 10) ? 47 : 41;
      float* path = out + 32 + (size_t)b * 512;
      const unsigned char* sp = &specL[(g * 11 + tau) * 47];
      for (int i = 0; i < len; ++i) path[khi - i] = (float)sp[i];
    }
  }
}

}  // namespace

extern "C" void kernel_launch(void* const* d_in, const int* in_sizes, int n_in,
                              void* d_out, int out_size, void* d_ws, size_t ws_size,
                              hipStream_t stream) {
  const int* sent     = (const int*)d_in[0];
  const float* embed  = (const float*)d_in[1];
  const float* w_ih_f = (const float*)d_in[2];
  const float* w_hh_f = (const float*)d_in[3];
  const float* b_ih_f = (const float*)d_in[4];
  const float* b_hh_f = (const float*)d_in[5];
  const float* w_ih_b = (const float*)d_in[6];
  const float* w_hh_b = (const float*)d_in[7];
  const float* b_ih_b = (const float*)d_in[8];
  const float* b_hh_b = (const float*)d_in[9];
  const float* h0     = (const float*)d_in[10];
  const float* c0     = (const float*)d_in[11];
  const float* w_out  = (const float*)d_in[12];
  const float* b_out  = (const float*)d_in[13];
  const float* trans  = (const float*)d_in[14];

  float* ws    = (float*)d_ws;
  float* x     = ws;                 // 16384*256 = 4,194,304
  float* hs_f  = x + 4194304;        // 32*512*256 = 4,194,304
  float* hs_b  = hs_f + 4194304;     // 4,194,304
  float* c_f   = hs_b + 4194304;     // 131,072
  float* c_b   = c_f + 131072;       // 131,072
  float* feats = c_b + 131072;       // 180,224
  // total ~12.9M floats = ~52 MiB of ws

  k_gather<<<4096, 256, 0, stream>>>(sent, embed, x);
  for (int t = 0; t < 32; ++t)
    k_step<<<512, 256, 0, stream>>>(
        x, w_ih_f, w_hh_f, b_ih_f, b_hh_f, w_ih_b, w_hh_b, b_ih_b, b_hh_b,
        h0, c0, hs_f, hs_b, c_f, c_b, t);
  k_out_gemm<<<4096, 256, 0, stream>>>(hs_f, hs_b, w_out, b_out, feats);
  k_viterbi<<<32, 128, 0, stream>>>(feats, trans, (float*)d_out);
}

// Round 7
// 1463.143 us; speedup vs baseline: 1.6433x; 1.1822x over previous
//
#include <hip/hip_runtime.h>
#include <math.h>

// BiLSTM-CRF fp32, round 7: split + outer-product GEMMs with SGPR weights.
// Layouts (all built on-device):
//   wiq/wtq[d][k][j][q]  k-major weights (q = gate i,f,g,o)
//   bq[d][j][q]          b_ih+b_hh
//   Gq[t][d][j][q][s]    x@W_ih^T + bias, s-innermost
//   ht_f/ht_b[33][j][s]  h states, slot 0 = h0^T, slot t+1 = after step t
//   ct[d][j][s]          c state (in-place)
//   wot[k(512)][tag]     w_out^T
//   featsT[tag][row]     feats transposed
// Output: d_out[0:32]=score, d_out[32:32+16384]=path (floats).

namespace {

constexpr int T_ = 11;
constexpr int HT = 256 * 512;        // one h slab (j-major, s-innermost)

__device__ __forceinline__ size_t gq_off(int t, int d, int j, int q, int s) {
  return ((((size_t)(t * 2 + d) * 256 + j) * 4 + q) * 512 + s);
}

// ---------------- K0: prep (transposes), flat 1,580,544 elements ----------------
__global__ __launch_bounds__(256) void k_prep(
    const float* __restrict__ w_ih_f, const float* __restrict__ w_ih_b,
    const float* __restrict__ w_hh_f, const float* __restrict__ w_hh_b,
    const float* __restrict__ b_ih_f, const float* __restrict__ b_hh_f,
    const float* __restrict__ b_ih_b, const float* __restrict__ b_hh_b,
    const float* __restrict__ h0, const float* __restrict__ c0,
    const float* __restrict__ w_out,
    float* __restrict__ wiq, float* __restrict__ wtq, float* __restrict__ bq,
    float* __restrict__ ct, float* __restrict__ ht_f, float* __restrict__ ht_b,
    float* __restrict__ wot) {
  const int i = blockIdx.x * 256 + threadIdx.x;
  if (i < 524288) {                                    // wiq from w_ih
    int d = i >> 18, r = i & 262143, gcr = r >> 8, k = r & 255;
    int q = gcr >> 8, j = gcr & 255;
    const float* w = d ? w_ih_b : w_ih_f;
    wiq[((size_t)(d * 256 + k) * 256 + j) * 4 + q] = w[gcr * 256 + k];
  } else if (i < 1048576) {                            // wtq from w_hh
    int r2 = i - 524288;
    int d = r2 >> 18, r = r2 & 262143, gcr = r >> 8, k = r & 255;
    int q = gcr >> 8, j = gcr & 255;
    const float* w = d ? w_hh_b : w_hh_f;
    wtq[((size_t)(d * 256 + k) * 256 + j) * 4 + q] = w[gcr * 256 + k];
  } else if (i < 1050624) {                            // bq
    int r = i - 1048576;
    int d = r >> 10, x = r & 1023, j = x >> 2, q = x & 3;
    const float* bi = d ? b_ih_b : b_ih_f;
    const float* bh = d ? b_hh_b : b_hh_f;
    bq[r] = bi[q * 256 + j] + bh[q * 256 + j];
  } else if (i < 1312768) {                            // ct from c0
    int r = i - 1050624;
    int d = r >> 17, y = r & 131071, j = y >> 9, s = y & 511;
    ct[r] = c0[((size_t)d * 512 + s) * 256 + j];
  } else if (i < 1574912) {                            // ht slot 0 from h0
    int r = i - 1312768;
    int d = r >> 17, y = r & 131071, j = y >> 9, s = y & 511;
    float v = h0[((size_t)d * 512 + s) * 256 + j];
    if (d == 0) ht_f[y] = v; else ht_b[y] = v;
  } else if (i < 1580544) {                            // wot from w_out
    int r = i - 1574912;
    int k = r / 11, tag = r - k * 11;
    wot[r] = w_out[tag * 512 + k];
  }
}

// ---------------- K1: Gq = x@W_ih^T + bias (embedding fused) ----------------
// grid 8192 = (rt 256) x (d 2) x (jg4 16); 256 thr = 4 waves; wave: 64 rows x
// 16 gc (4 j x 4 q). lane = row. A staged via LDS transpose; W via s_load.
__global__ __launch_bounds__(256) void k_ggemm(
    const int* __restrict__ sent, const float* __restrict__ embed,
    const float* __restrict__ wiq, const float* __restrict__ bq,
    float* __restrict__ Gq) {
  __shared__ float As[64][67];
  const int tid = threadIdx.x;
  const int bid = blockIdx.x;
  const int jg4 = bid & 15;
  const int d = (bid >> 4) & 1;
  const int rt = bid >> 5;
  const int wid = __builtin_amdgcn_readfirstlane(tid >> 6);
  const int lane = tid & 63;
  const int row0 = rt * 64;
  const int t = row0 >> 9;                 // uniform (64 | 512)
  const int sb = (row0 & 511) + lane;      // this lane's s
  const int j0 = (jg4 * 4 + wid) * 4;

  const int rr = tid >> 2, eq = tid & 3;   // staging: 4 lanes per row
  const int tok = sent[row0 + rr];
  const float* erow = embed + (size_t)tok * 256 + eq * 16;

  float acc[16];
#pragma unroll
  for (int g = 0; g < 16; ++g) acc[g] = 0.f;

  const float* wbase = wiq + (size_t)d * 256 * 1024;

  for (int ci = 0; ci < 4; ++ci) {
    const int k0 = ci * 64;
    const float* ep = erow + k0;
    float4 v0 = *(const float4*)(ep);
    float4 v1 = *(const float4*)(ep + 4);
    float4 v2 = *(const float4*)(ep + 8);
    float4 v3 = *(const float4*)(ep + 12);
    const int kb = eq * 16;
    As[kb + 0][rr] = v0.x;  As[kb + 1][rr] = v0.y;  As[kb + 2][rr] = v0.z;  As[kb + 3][rr] = v0.w;
    As[kb + 4][rr] = v1.x;  As[kb + 5][rr] = v1.y;  As[kb + 6][rr] = v1.z;  As[kb + 7][rr] = v1.w;
    As[kb + 8][rr] = v2.x;  As[kb + 9][rr] = v2.y;  As[kb + 10][rr] = v2.z; As[kb + 11][rr] = v2.w;
    As[kb + 12][rr] = v3.x; As[kb + 13][rr] = v3.y; As[kb + 14][rr] = v3.z; As[kb + 15][rr] = v3.w;
    __syncthreads();
#pragma unroll 2
    for (int kk = 0; kk < 64; ++kk) {
      float a = As[kk][lane];
      const float* wp = wbase + (size_t)(k0 + kk) * 1024 + j0 * 4;  // uniform
#pragma unroll
      for (int g = 0; g < 16; ++g) acc[g] = fmaf(a, wp[g], acc[g]);
    }
    __syncthreads();
  }
  const float* bp = bq + ((size_t)d * 256 + j0) * 4;
#pragma unroll
  for (int g = 0; g < 16; ++g) {
    int jj = g >> 2, q = g & 3;
    Gq[gq_off(t, d, j0 + jj, q, sb)] = acc[g] + bp[g];
  }
}

// ---------------- K2: recurrent step (h@W_hh^T + Gq -> pointwise) ----------------
// grid 1024 = (d 2) x (jg 64) x (stile 8); 256 thr = 4 waves (kh x gt).
// wave: 64 s x 8 gc (2 j x 4 q), K-half 128. lane = s.
__global__ __launch_bounds__(256) void k_rstep(
    const float* __restrict__ wtq, const float* __restrict__ Gq,
    float* __restrict__ ht_f, float* __restrict__ ht_b,
    float* __restrict__ ct, int t) {
  __shared__ float red[2][8][64];
  const int tid = threadIdx.x;
  const int bid = blockIdx.x;
  const int stile = bid & 7;
  const int jg = (bid >> 3) & 63;
  const int d = bid >> 9;
  const int wid = __builtin_amdgcn_readfirstlane(tid >> 6);
  const int lane = tid & 63;
  const int kh = wid >> 1, gt = wid & 1;
  const int s0 = stile * 64;
  const int j0g = jg * 4 + gt * 2;          // this wave's 2 j's
  const int tt = d ? 31 - t : t;

  float* htX = d ? ht_b : ht_f;
  const float* hprev = htX + (size_t)t * HT;
  const float* wbase = wtq + (size_t)d * 256 * 1024 + j0g * 4;

  float acc[8];
#pragma unroll
  for (int g = 0; g < 8; ++g) acc[g] = 0.f;

  const int kbeg = kh * 128;
#pragma unroll 4
  for (int kk = kbeg; kk < kbeg + 128; ++kk) {
    float a = hprev[(size_t)kk * 512 + s0 + lane];
    const float* wp = wbase + (size_t)kk * 1024;    // uniform -> s_load
#pragma unroll
    for (int g = 0; g < 8; ++g) acc[g] = fmaf(a, wp[g], acc[g]);
  }

  if (kh == 1) {
#pragma unroll
    for (int g = 0; g < 8; ++g) red[gt][g][lane] = acc[g];
  }
  __syncthreads();
  if (kh == 0) {
#pragma unroll
    for (int g = 0; g < 8; ++g) acc[g] += red[gt][g][lane];
#pragma unroll
    for (int jj = 0; jj < 2; ++jj) {
      const int j = j0g + jj;
      const float* gp = Gq + gq_off(tt, d, j, 0, s0 + lane);
      float gi = acc[jj * 4 + 0] + gp[0 * 512];
      float gf = acc[jj * 4 + 1] + gp[1 * 512];
      float gg = acc[jj * 4 + 2] + gp[2 * 512];
      float go = acc[jj * 4 + 3] + gp[3 * 512];
      float si = 1.f / (1.f + expf(-gi));
      float sf = 1.f / (1.f + expf(-gf));
      float tg = tanhf(gg);
      float so = 1.f / (1.f + expf(-go));
      size_t coff = ((size_t)d * 256 + j) * 512 + s0 + lane;
      float cp = ct[coff];
      float cn = sf * cp + si * tg;
      float hn = so * tanhf(cn);
      ct[coff] = cn;
      htX[(size_t)(t + 1) * HT + (size_t)j * 512 + s0 + lane] = hn;
    }
  }
}

// ---------------- K3: featsT = [hf|hb]@w_out^T + b_out ----------------
// grid 256 = (t 32) x (stile 8); 4 waves = K-chunks of 128; lane = s.
__global__ __launch_bounds__(256) void k_out(
    const float* __restrict__ ht_f, const float* __restrict__ ht_b,
    const float* __restrict__ wot, const float* __restrict__ b_out,
    float* __restrict__ featsT) {
  __shared__ float red[4][11][64];
  const int tid = threadIdx.x;
  const int bid = blockIdx.x;
  const int t = bid >> 3, stile = bid & 7;
  const int wid = __builtin_amdgcn_readfirstlane(tid >> 6);
  const int lane = tid & 63;
  const int s0 = stile * 64;
  const int kg0 = wid * 128;
  const float* src = (wid < 2)
      ? ht_f + (size_t)(t + 1) * HT + (size_t)kg0 * 512
      : ht_b + (size_t)(32 - t) * HT + (size_t)(kg0 - 256) * 512;

  float acc[11];
#pragma unroll
  for (int g = 0; g < 11; ++g) acc[g] = 0.f;
#pragma unroll 4
  for (int kk = 0; kk < 128; ++kk) {
    float a = src[(size_t)kk * 512 + s0 + lane];
    const float* wp = wot + (size_t)(kg0 + kk) * 11;   // uniform
#pragma unroll
    for (int g = 0; g < 11; ++g) acc[g] = fmaf(a, wp[g], acc[g]);
  }
#pragma unroll
  for (int g = 0; g < 11; ++g) red[wid][g][lane] = acc[g];
  __syncthreads();
  if (wid == 0) {
#pragma unroll
    for (int g = 0; g < 11; ++g) {
      float v = red[0][g][lane] + red[1][g][lane] + red[2][g][lane] +
                red[3][g][lane] + b_out[g];
      featsT[(size_t)g * 16384 + t * 512 + s0 + lane] = v;
    }
  }
}

// ---------------- K4: Viterbi (round-6 version, featsT input) ----------------
#define PAIR(va, ia, vb, ib, vo, io) { bool c_ = (va) >= (vb); vo = c_ ? (va) : (vb); io = c_ ? (ia) : (ib); }

__global__ __launch_bounds__(128) void k_viterbi(const float* __restrict__ featsT,
                                                 const float* __restrict__ trans,
                                                 float* __restrict__ out) {
  __shared__ float fl[512 * T_];
  __shared__ unsigned char psiL[511 * T_];
  __shared__ unsigned char specL[121 * 47];
  __shared__ unsigned char selL[16];
  __shared__ int lastL;
  __shared__ float scoreL;
  const int b = blockIdx.x, tid = threadIdx.x;
  for (int i = tid; i < 512 * T_; i += 128) {
    int tag = i >> 9, s = i & 511;
    fl[s * T_ + tag] = featsT[(size_t)tag * 16384 + b * 512 + s];
  }
  __syncthreads();

  if (tid < 64) {
    const int lane = tid;
    const int to = (lane < T_) ? lane : 0;
    float tr[T_];
#pragma unroll
    for (int f = 0; f < T_; ++f) tr[f] = trans[to * T_ + f];
    float delta = (lane == 9) ? 0.f : -10000.f;   // START=9

    for (int s = 1; s < 512; ++s) {
      float v0 = tr[0] + __shfl(delta, 0, 64);
      float v1 = tr[1] + __shfl(delta, 1, 64);
      float v2 = tr[2] + __shfl(delta, 2, 64);
      float v3 = tr[3] + __shfl(delta, 3, 64);
      float v4 = tr[4] + __shfl(delta, 4, 64);
      float v5 = tr[5] + __shfl(delta, 5, 64);
      float v6 = tr[6] + __shfl(delta, 6, 64);
      float v7 = tr[7] + __shfl(delta, 7, 64);
      float v8 = tr[8] + __shfl(delta, 8, 64);
      float v9 = tr[9] + __shfl(delta, 9, 64);
      float v10 = tr[10] + __shfl(delta, 10, 64);
      float mA, mB, mC, mD, mE, mG, mH, mI, mJ, m;
      int iA, iB, iC, iD, iE, iG, iH, iI, iJ, am;
      PAIR(v0, 0, v1, 1, mA, iA); PAIR(v2, 2, v3, 3, mB, iB);
      PAIR(v4, 4, v5, 5, mC, iC); PAIR(v6, 6, v7, 7, mD, iD);
      PAIR(v8, 8, v9, 9, mE, iE);
      PAIR(mA, iA, mB, iB, mG, iG); PAIR(mC, iC, mD, iD, mH, iH);
      PAIR(mE, iE, v10, 10, mI, iI);
      PAIR(mG, iG, mH, iH, mJ, iJ);
      PAIR(mJ, iJ, mI, iI, m, am);
      if (lane < T_) psiL[(s - 1) * T_ + lane] = (unsigned char)am;
      delta = m + fl[s * T_ + to];
    }
    float d0 = __shfl(delta, 0, 64), d1 = __shfl(delta, 1, 64);
    float d2 = __shfl(delta, 2, 64), d3 = __shfl(delta, 3, 64);
    float d4 = __shfl(delta, 4, 64), d5 = __shfl(delta, 5, 64);
    float d6 = __shfl(delta, 6, 64), d7 = __shfl(delta, 7, 64);
    float d8 = __shfl(delta, 8, 64), d9 = __shfl(delta, 9, 64);
    float d10 = __shfl(delta, 10, 64);
    float mA, mB, mC, mD, mE, mG, mH, mI, mJ, m;
    int iA, iB, iC, iD, iE, iG, iH, iI, iJ, am;
    PAIR(d0, 0, d1, 1, mA, iA); PAIR(d2, 2, d3, 3, mB, iB);
    PAIR(d4, 4, d5, 5, mC, iC); PAIR(d6, 6, d7, 7, mD, iD);
    PAIR(d8, 8, d9, 9, mE, iE);
    PAIR(mA, iA, mB, iB, mG, iG); PAIR(mC, iC, mD, iD, mH, iH);
    PAIR(mE, iE, d10, 10, mI, iI);
    PAIR(mG, iG, mH, iH, mJ, iJ);
    PAIR(mJ, iJ, mI, iI, m, am);
    if (lane == 0) { lastL = am; scoreL = m; }
  }
  __syncthreads();

  const int last = lastL;
  if (tid < 121) {
    const int g = tid / 11, tau = tid - g * 11;
    const int khi = 510 - 47 * g;
    const int len = (g < 10) ? 47 : 41;
    int cur = tau;
    unsigned char* sp = &specL[(g * 11 + tau) * 47];
    for (int i = 0; i < len; ++i) {
      cur = psiL[(khi - i) * T_ + cur];
      sp[i] = (unsigned char)cur;
    }
  }
  __syncthreads();
  if (tid == 0) {
    int cur = last;
    for (int g = 0; g < 11; ++g) {
      selL[g] = (unsigned char)cur;
      int len = (g < 10) ? 47 : 41;
      cur = specL[(g * 11 + cur) * 47 + (len - 1)];
    }
    out[b] = scoreL;
    out[32 + (size_t)b * 512 + 511] = (float)last;
  }
  __syncthreads();
  if (tid < 121) {
    const int g = tid / 11, tau = tid - g * 11;
    if (tau == selL[g]) {
      const int khi = 510 - 47 * g;
      const int len = (g < 10) ? 47 : 41;
      float* path = out + 32 + (size_t)b * 512;
      const unsigned char* sp = &specL[(g * 11 + tau) * 47];
      for (int i = 0; i < len; ++i) path[khi - i] = (float)sp[i];
    }
  }
}

}  // namespace

extern "C" void kernel_launch(void* const* d_in, const int* in_sizes, int n_in,
                              void* d_out, int out_size, void* d_ws, size_t ws_size,
                              hipStream_t stream) {
  const int* sent     = (const int*)d_in[0];
  const float* embed  = (const float*)d_in[1];
  const float* w_ih_f = (const float*)d_in[2];
  const float* w_hh_f = (const float*)d_in[3];
  const float* b_ih_f = (const float*)d_in[4];
  const float* b_hh_f = (const float*)d_in[5];
  const float* w_ih_b = (const float*)d_in[6];
  const float* w_hh_b = (const float*)d_in[7];
  const float* b_ih_b = (const float*)d_in[8];
  const float* b_hh_b = (const float*)d_in[9];
  const float* h0     = (const float*)d_in[10];
  const float* c0     = (const float*)d_in[11];
  const float* w_out  = (const float*)d_in[12];
  const float* b_out  = (const float*)d_in[13];
  const float* trans  = (const float*)d_in[14];

  float* ws = (float*)d_ws;
  float* Gq     = ws;                      // 33,554,432
  float* ht_f   = Gq + 33554432;           //  4,325,376  (33 slabs)
  float* ht_b   = ht_f + 4325376;          //  4,325,376
  float* ct     = ht_b + 4325376;          //    262,144
  float* wiq    = ct + 262144;             //    524,288
  float* wtq    = wiq + 524288;            //    524,288
  float* bq     = wtq + 524288;            //      2,048
  float* wot    = bq + 2048;               //      5,632
  float* featsT = wot + 5632;              //    180,224
  // total 43,703,808 floats = 166.7 MiB (< round-1-proven 177.7 MiB)

  k_prep<<<6174, 256, 0, stream>>>(w_ih_f, w_ih_b, w_hh_f, w_hh_b,
                                   b_ih_f, b_hh_f, b_ih_b, b_hh_b,
                                   h0, c0, w_out,
                                   wiq, wtq, bq, ct, ht_f, ht_b, wot);
  k_ggemm<<<8192, 256, 0, stream>>>(sent, embed, wiq, bq, Gq);
  for (int t = 0; t < 32; ++t)
    k_rstep<<<1024, 256, 0, stream>>>(wtq, Gq, ht_f, ht_b, ct, t);
  k_out<<<256, 256, 0, stream>>>(ht_f, ht_b, wot, b_out, featsT);
  k_viterbi<<<32, 128, 0, stream>>>(featsT, trans, (float*)d_out);
}

// Round 8
// 841.935 us; speedup vs baseline: 2.8558x; 1.7378x over previous
//
#include <hip/hip_runtime.h>
#include <math.h>

// BiLSTM-CRF fp32, round 8: rstep v2 — lane=j outer-product form.
// wt3[xcd][k][jl][q]: xcd=(d*4+sl) owns j-slice sl*64..+64; per k, lane jl
// loads float4 = 4 gates of its j (coalesced); h[k][s-quad] is wave-uniform.
// Thread owns 4 gates x 4 s -> pointwise fully in registers.
// Other kernels unchanged from round 7.
// Output: d_out[0:32]=score, d_out[32:32+16384]=path (floats).

namespace {

constexpr int T_ = 11;
constexpr int HT = 256 * 512;        // one h slab (j-major, s-innermost)

__device__ __forceinline__ size_t gq_off(int t, int d, int j, int q, int s) {
  return ((((size_t)(t * 2 + d) * 256 + j) * 4 + q) * 512 + s);
}

// ---------------- K0: prep (transposes), flat 1,580,544 elements ----------------
__global__ __launch_bounds__(256) void k_prep(
    const float* __restrict__ w_ih_f, const float* __restrict__ w_ih_b,
    const float* __restrict__ w_hh_f, const float* __restrict__ w_hh_b,
    const float* __restrict__ b_ih_f, const float* __restrict__ b_hh_f,
    const float* __restrict__ b_ih_b, const float* __restrict__ b_hh_b,
    const float* __restrict__ h0, const float* __restrict__ c0,
    const float* __restrict__ w_out,
    float* __restrict__ wiq, float* __restrict__ wt3, float* __restrict__ bq,
    float* __restrict__ ct, float* __restrict__ ht_f, float* __restrict__ ht_b,
    float* __restrict__ wot) {
  const int i = blockIdx.x * 256 + threadIdx.x;
  if (i < 524288) {                                    // wiq from w_ih (for ggemm)
    int d = i >> 18, r = i & 262143, gcr = r >> 8, k = r & 255;
    int q = gcr >> 8, j = gcr & 255;
    const float* w = d ? w_ih_b : w_ih_f;
    wiq[((size_t)(d * 256 + k) * 256 + j) * 4 + q] = w[gcr * 256 + k];
  } else if (i < 1048576) {                            // wt3 from w_hh
    int r = i - 524288;                                // [xcd 3][k 8][jl 6][q 2]
    int q = r & 3, jl = (r >> 2) & 63, k = (r >> 8) & 255, xcd = r >> 16;
    int d = xcd >> 2, sl = xcd & 3;
    int j = sl * 64 + jl;
    const float* w = d ? w_hh_b : w_hh_f;
    wt3[r] = w[(q * 256 + j) * 256 + k];
  } else if (i < 1050624) {                            // bq
    int r = i - 1048576;
    int d = r >> 10, x = r & 1023, j = x >> 2, q = x & 3;
    const float* bi = d ? b_ih_b : b_ih_f;
    const float* bh = d ? b_hh_b : b_hh_f;
    bq[r] = bi[q * 256 + j] + bh[q * 256 + j];
  } else if (i < 1312768) {                            // ct from c0
    int r = i - 1050624;
    int d = r >> 17, y = r & 131071, j = y >> 9, s = y & 511;
    ct[r] = c0[((size_t)d * 512 + s) * 256 + j];
  } else if (i < 1574912) {                            // ht slot 0 from h0
    int r = i - 1312768;
    int d = r >> 17, y = r & 131071, j = y >> 9, s = y & 511;
    float v = h0[((size_t)d * 512 + s) * 256 + j];
    if (d == 0) ht_f[y] = v; else ht_b[y] = v;
  } else if (i < 1580544) {                            // wot from w_out
    int r = i - 1574912;
    int k = r / 11, tag = r - k * 11;
    wot[r] = w_out[tag * 512 + k];
  }
}

// ---------------- K1: Gq = x@W_ih^T + bias (embedding fused) ----------------
__global__ __launch_bounds__(256) void k_ggemm(
    const int* __restrict__ sent, const float* __restrict__ embed,
    const float* __restrict__ wiq, const float* __restrict__ bq,
    float* __restrict__ Gq) {
  __shared__ float As[64][67];
  const int tid = threadIdx.x;
  const int bid = blockIdx.x;
  const int jg4 = bid & 15;
  const int d = (bid >> 4) & 1;
  const int rt = bid >> 5;
  const int wid = __builtin_amdgcn_readfirstlane(tid >> 6);
  const int lane = tid & 63;
  const int row0 = rt * 64;
  const int t = row0 >> 9;
  const int sb = (row0 & 511) + lane;
  const int j0 = (jg4 * 4 + wid) * 4;

  const int rr = tid >> 2, eq = tid & 3;
  const int tok = sent[row0 + rr];
  const float* erow = embed + (size_t)tok * 256 + eq * 16;

  float acc[16];
#pragma unroll
  for (int g = 0; g < 16; ++g) acc[g] = 0.f;

  const float* wbase = wiq + (size_t)d * 256 * 1024;

  for (int ci = 0; ci < 4; ++ci) {
    const int k0 = ci * 64;
    const float* ep = erow + k0;
    float4 v0 = *(const float4*)(ep);
    float4 v1 = *(const float4*)(ep + 4);
    float4 v2 = *(const float4*)(ep + 8);
    float4 v3 = *(const float4*)(ep + 12);
    const int kb = eq * 16;
    As[kb + 0][rr] = v0.x;  As[kb + 1][rr] = v0.y;  As[kb + 2][rr] = v0.z;  As[kb + 3][rr] = v0.w;
    As[kb + 4][rr] = v1.x;  As[kb + 5][rr] = v1.y;  As[kb + 6][rr] = v1.z;  As[kb + 7][rr] = v1.w;
    As[kb + 8][rr] = v2.x;  As[kb + 9][rr] = v2.y;  As[kb + 10][rr] = v2.z; As[kb + 11][rr] = v2.w;
    As[kb + 12][rr] = v3.x; As[kb + 13][rr] = v3.y; As[kb + 14][rr] = v3.z; As[kb + 15][rr] = v3.w;
    __syncthreads();
#pragma unroll 2
    for (int kk = 0; kk < 64; ++kk) {
      float a = As[kk][lane];
      const float* wp = wbase + (size_t)(k0 + kk) * 1024 + j0 * 4;
#pragma unroll
      for (int g = 0; g < 16; ++g) acc[g] = fmaf(a, wp[g], acc[g]);
    }
    __syncthreads();
  }
  const float* bp = bq + ((size_t)d * 256 + j0) * 4;
#pragma unroll
  for (int g = 0; g < 16; ++g) {
    int jj = g >> 2, q = g & 3;
    Gq[gq_off(t, d, j0 + jj, q, sb)] = acc[g] + bp[g];
  }
}

// ---------------- K2: rstep v2 — lane=j outer product ----------------
// grid 256 = (xcd 8: d*4+sl) x (sg 32); 512 thr = 8 waves = (sq 4) x (kh 2).
// Thread (jl, sq, kh): acc[q 4][ss 4] over K-half 128.
__global__ __launch_bounds__(512) void k_rstep(
    const float* __restrict__ wt3, const float* __restrict__ Gq,
    float* __restrict__ ht_f, float* __restrict__ ht_b,
    float* __restrict__ ct, int t) {
  __shared__ float red[256][17];
  const int tid = threadIdx.x;
  const int bid = blockIdx.x;
  const int xcd = bid & 7, sg = bid >> 3;
  const int d = xcd >> 2, sl = xcd & 3;
  const int kh = __builtin_amdgcn_readfirstlane(tid >> 8);
  const int sq = __builtin_amdgcn_readfirstlane((tid >> 6) & 3);
  const int rem = tid & 255;
  const int jl = tid & 63;
  const int s0 = sg * 16 + sq * 4;
  const int j = sl * 64 + jl;
  const int tt = d ? 31 - t : t;

  float* htX = d ? ht_b : ht_f;
  const float* hprev = htX + (size_t)t * HT;                 // [k 256][s 512]
  const float* wp = wt3 + ((size_t)xcd * 256 + (size_t)kh * 128) * 256 + jl * 4;
  const float* hp = hprev + (size_t)kh * 128 * 512 + s0;

  float acc[4][4];
#pragma unroll
  for (int q = 0; q < 4; ++q)
#pragma unroll
    for (int ss = 0; ss < 4; ++ss) acc[q][ss] = 0.f;

#pragma unroll 8
  for (int k = 0; k < 128; ++k) {
    const float4 w4 = *(const float4*)(wp + (size_t)k * 256);   // per-lane, coalesced
    const float4 h4 = *(const float4*)(hp + (size_t)k * 512);   // wave-uniform
    acc[0][0] = fmaf(w4.x, h4.x, acc[0][0]);
    acc[0][1] = fmaf(w4.x, h4.y, acc[0][1]);
    acc[0][2] = fmaf(w4.x, h4.z, acc[0][2]);
    acc[0][3] = fmaf(w4.x, h4.w, acc[0][3]);
    acc[1][0] = fmaf(w4.y, h4.x, acc[1][0]);
    acc[1][1] = fmaf(w4.y, h4.y, acc[1][1]);
    acc[1][2] = fmaf(w4.y, h4.z, acc[1][2]);
    acc[1][3] = fmaf(w4.y, h4.w, acc[1][3]);
    acc[2][0] = fmaf(w4.z, h4.x, acc[2][0]);
    acc[2][1] = fmaf(w4.z, h4.y, acc[2][1]);
    acc[2][2] = fmaf(w4.z, h4.z, acc[2][2]);
    acc[2][3] = fmaf(w4.z, h4.w, acc[2][3]);
    acc[3][0] = fmaf(w4.w, h4.x, acc[3][0]);
    acc[3][1] = fmaf(w4.w, h4.y, acc[3][1]);
    acc[3][2] = fmaf(w4.w, h4.z, acc[3][2]);
    acc[3][3] = fmaf(w4.w, h4.w, acc[3][3]);
  }

  if (kh == 1) {
#pragma unroll
    for (int q = 0; q < 4; ++q)
#pragma unroll
      for (int ss = 0; ss < 4; ++ss) red[rem][q * 4 + ss] = acc[q][ss];
  }
  __syncthreads();
  if (kh == 0) {
#pragma unroll
    for (int q = 0; q < 4; ++q)
#pragma unroll
      for (int ss = 0; ss < 4; ++ss) acc[q][ss] += red[rem][q * 4 + ss];

    const float* gp = Gq + gq_off(tt, d, j, 0, s0);
    float4 gI = *(const float4*)(gp);
    float4 gF = *(const float4*)(gp + 512);
    float4 gG = *(const float4*)(gp + 1024);
    float4 gO = *(const float4*)(gp + 1536);
    const size_t coff = ((size_t)d * 256 + j) * 512 + s0;
    float4 c4 = *(const float4*)(ct + coff);
    float giA[4] = {gI.x, gI.y, gI.z, gI.w};
    float gfA[4] = {gF.x, gF.y, gF.z, gF.w};
    float ggA[4] = {gG.x, gG.y, gG.z, gG.w};
    float goA[4] = {gO.x, gO.y, gO.z, gO.w};
    float cA[4]  = {c4.x, c4.y, c4.z, c4.w};
    float cnA[4], hA[4];
#pragma unroll
    for (int ss = 0; ss < 4; ++ss) {
      float gi = acc[0][ss] + giA[ss];
      float gf = acc[1][ss] + gfA[ss];
      float gg = acc[2][ss] + ggA[ss];
      float go = acc[3][ss] + goA[ss];
      float si = 1.f / (1.f + expf(-gi));
      float sf = 1.f / (1.f + expf(-gf));
      float tg = tanhf(gg);
      float so = 1.f / (1.f + expf(-go));
      float cn = sf * cA[ss] + si * tg;
      cnA[ss] = cn;
      hA[ss] = so * tanhf(cn);
    }
    *(float4*)(ct + coff) = make_float4(cnA[0], cnA[1], cnA[2], cnA[3]);
    float* ho = htX + (size_t)(t + 1) * HT + (size_t)j * 512 + s0;
    *(float4*)ho = make_float4(hA[0], hA[1], hA[2], hA[3]);
  }
}

// ---------------- K3: featsT = [hf|hb]@w_out^T + b_out ----------------
__global__ __launch_bounds__(256) void k_out(
    const float* __restrict__ ht_f, const float* __restrict__ ht_b,
    const float* __restrict__ wot, const float* __restrict__ b_out,
    float* __restrict__ featsT) {
  __shared__ float red[4][11][64];
  const int tid = threadIdx.x;
  const int bid = blockIdx.x;
  const int t = bid >> 3, stile = bid & 7;
  const int wid = __builtin_amdgcn_readfirstlane(tid >> 6);
  const int lane = tid & 63;
  const int s0 = stile * 64;
  const int kg0 = wid * 128;
  const float* src = (wid < 2)
      ? ht_f + (size_t)(t + 1) * HT + (size_t)kg0 * 512
      : ht_b + (size_t)(32 - t) * HT + (size_t)(kg0 - 256) * 512;

  float acc[11];
#pragma unroll
  for (int g = 0; g < 11; ++g) acc[g] = 0.f;
#pragma unroll 4
  for (int kk = 0; kk < 128; ++kk) {
    float a = src[(size_t)kk * 512 + s0 + lane];
    const float* wp = wot + (size_t)(kg0 + kk) * 11;
#pragma unroll
    for (int g = 0; g < 11; ++g) acc[g] = fmaf(a, wp[g], acc[g]);
  }
#pragma unroll
  for (int g = 0; g < 11; ++g) red[wid][g][lane] = acc[g];
  __syncthreads();
  if (wid == 0) {
#pragma unroll
    for (int g = 0; g < 11; ++g) {
      float v = red[0][g][lane] + red[1][g][lane] + red[2][g][lane] +
                red[3][g][lane] + b_out[g];
      featsT[(size_t)g * 16384 + t * 512 + s0 + lane] = v;
    }
  }
}

// ---------------- K4: Viterbi ----------------
#define PAIR(va, ia, vb, ib, vo, io) { bool c_ = (va) >= (vb); vo = c_ ? (va) : (vb); io = c_ ? (ia) : (ib); }

__global__ __launch_bounds__(128) void k_viterbi(const float* __restrict__ featsT,
                                                 const float* __restrict__ trans,
                                                 float* __restrict__ out) {
  __shared__ float fl[512 * T_];
  __shared__ unsigned char psiL[511 * T_];
  __shared__ unsigned char specL[121 * 47];
  __shared__ unsigned char selL[16];
  __shared__ int lastL;
  __shared__ float scoreL;
  const int b = blockIdx.x, tid = threadIdx.x;
  for (int i = tid; i < 512 * T_; i += 128) {
    int tag = i >> 9, s = i & 511;
    fl[s * T_ + tag] = featsT[(size_t)tag * 16384 + b * 512 + s];
  }
  __syncthreads();

  if (tid < 64) {
    const int lane = tid;
    const int to = (lane < T_) ? lane : 0;
    float tr[T_];
#pragma unroll
    for (int f = 0; f < T_; ++f) tr[f] = trans[to * T_ + f];
    float delta = (lane == 9) ? 0.f : -10000.f;   // START=9

    for (int s = 1; s < 512; ++s) {
      float v0 = tr[0] + __shfl(delta, 0, 64);
      float v1 = tr[1] + __shfl(delta, 1, 64);
      float v2 = tr[2] + __shfl(delta, 2, 64);
      float v3 = tr[3] + __shfl(delta, 3, 64);
      float v4 = tr[4] + __shfl(delta, 4, 64);
      float v5 = tr[5] + __shfl(delta, 5, 64);
      float v6 = tr[6] + __shfl(delta, 6, 64);
      float v7 = tr[7] + __shfl(delta, 7, 64);
      float v8 = tr[8] + __shfl(delta, 8, 64);
      float v9 = tr[9] + __shfl(delta, 9, 64);
      float v10 = tr[10] + __shfl(delta, 10, 64);
      float mA, mB, mC, mD, mE, mG, mH, mI, mJ, m;
      int iA, iB, iC, iD, iE, iG, iH, iI, iJ, am;
      PAIR(v0, 0, v1, 1, mA, iA); PAIR(v2, 2, v3, 3, mB, iB);
      PAIR(v4, 4, v5, 5, mC, iC); PAIR(v6, 6, v7, 7, mD, iD);
      PAIR(v8, 8, v9, 9, mE, iE);
      PAIR(mA, iA, mB, iB, mG, iG); PAIR(mC, iC, mD, iD, mH, iH);
      PAIR(mE, iE, v10, 10, mI, iI);
      PAIR(mG, iG, mH, iH, mJ, iJ);
      PAIR(mJ, iJ, mI, iI, m, am);
      if (lane < T_) psiL[(s - 1) * T_ + lane] = (unsigned char)am;
      delta = m + fl[s * T_ + to];
    }
    float d0 = __shfl(delta, 0, 64), d1 = __shfl(delta, 1, 64);
    float d2 = __shfl(delta, 2, 64), d3 = __shfl(delta, 3, 64);
    float d4 = __shfl(delta, 4, 64), d5 = __shfl(delta, 5, 64);
    float d6 = __shfl(delta, 6, 64), d7 = __shfl(delta, 7, 64);
    float d8 = __shfl(delta, 8, 64), d9 = __shfl(delta, 9, 64);
    float d10 = __shfl(delta, 10, 64);
    float mA, mB, mC, mD, mE, mG, mH, mI, mJ, m;
    int iA, iB, iC, iD, iE, iG, iH, iI, iJ, am;
    PAIR(d0, 0, d1, 1, mA, iA); PAIR(d2, 2, d3, 3, mB, iB);
    PAIR(d4, 4, d5, 5, mC, iC); PAIR(d6, 6, d7, 7, mD, iD);
    PAIR(d8, 8, d9, 9, mE, iE);
    PAIR(mA, iA, mB, iB, mG, iG); PAIR(mC, iC, mD, iD, mH, iH);
    PAIR(mE, iE, d10, 10, mI, iI);
    PAIR(mG, iG, mH, iH, mJ, iJ);
    PAIR(mJ, iJ, mI, iI, m, am);
    if (lane == 0) { lastL = am; scoreL = m; }
  }
  __syncthreads();

  const int last = lastL;
  if (tid < 121) {
    const int g = tid / 11, tau = tid - g * 11;
    const int khi = 510 - 47 * g;
    const int len = (g < 10) ? 47 : 41;
    int cur = tau;
    unsigned char* sp = &specL[(g * 11 + tau) * 47];
    for (int i = 0; i < len; ++i) {
      cur = psiL[(khi - i) * T_ + cur];
      sp[i] = (unsigned char)cur;
    }
  }
  __syncthreads();
  if (tid == 0) {
    int cur = last;
    for (int g = 0; g < 11; ++g) {
      selL[g] = (unsigned char)cur;
      int len = (g < 10) ? 47 : 41;
      cur = specL[(g * 11 + cur) * 47 + (len - 1)];
    }
    out[b] = scoreL;
    out[32 + (size_t)b * 512 + 511] = (float)last;
  }
  __syncthreads();
  if (tid < 121) {
    const int g = tid / 11, tau = tid - g * 11;
    if (tau == selL[g]) {
      const int khi = 510 - 47 * g;
      const int len = (g < 10) ? 47 : 41;
      float* path = out + 32 + (size_t)b * 512;
      const unsigned char* sp = &specL[(g * 11 + tau) * 47];
      for (int i = 0; i < len; ++i) path[khi - i] = (float)sp[i];
    }
  }
}

}  // namespace

extern "C" void kernel_launch(void* const* d_in, const int* in_sizes, int n_in,
                              void* d_out, int out_size, void* d_ws, size_t ws_size,
                              hipStream_t stream) {
  const int* sent     = (const int*)d_in[0];
  const float* embed  = (const float*)d_in[1];
  const float* w_ih_f = (const float*)d_in[2];
  const float* w_hh_f = (const float*)d_in[3];
  const float* b_ih_f = (const float*)d_in[4];
  const float* b_hh_f = (const float*)d_in[5];
  const float* w_ih_b = (const float*)d_in[6];
  const float* w_hh_b = (const float*)d_in[7];
  const float* b_ih_b = (const float*)d_in[8];
  const float* b_hh_b = (const float*)d_in[9];
  const float* h0     = (const float*)d_in[10];
  const float* c0     = (const float*)d_in[11];
  const float* w_out  = (const float*)d_in[12];
  const float* b_out  = (const float*)d_in[13];
  const float* trans  = (const float*)d_in[14];

  float* ws = (float*)d_ws;
  float* Gq     = ws;                      // 33,554,432
  float* ht_f   = Gq + 33554432;           //  4,325,376  (33 slabs)
  float* ht_b   = ht_f + 4325376;          //  4,325,376
  float* ct     = ht_b + 4325376;          //    262,144
  float* wiq    = ct + 262144;             //    524,288
  float* wt3    = wiq + 524288;            //    524,288
  float* bq     = wt3 + 524288;            //      2,048
  float* wot    = bq + 2048;               //      5,632
  float* featsT = wot + 5632;              //    180,224
  // total 43,703,808 floats = 166.7 MiB

  k_prep<<<6174, 256, 0, stream>>>(w_ih_f, w_ih_b, w_hh_f, w_hh_b,
                                   b_ih_f, b_hh_f, b_ih_b, b_hh_b,
                                   h0, c0, w_out,
                                   wiq, wt3, bq, ct, ht_f, ht_b, wot);
  k_ggemm<<<8192, 256, 0, stream>>>(sent, embed, wiq, bq, Gq);
  for (int t = 0; t < 32; ++t)
    k_rstep<<<256, 512, 0, stream>>>(wt3, Gq, ht_f, ht_b, ct, t);
  k_out<<<256, 256, 0, stream>>>(ht_f, ht_b, wot, b_out, featsT);
  k_viterbi<<<32, 128, 0, stream>>>(featsT, trans, (float*)d_out);
}

// Round 9
// 816.734 us; speedup vs baseline: 2.9439x; 1.0309x over previous
//
#include <hip/hip_runtime.h>
#include <math.h>

// BiLSTM-CRF fp32, round 9.
// rstep v3: lane=(jl,q) over 16-j slice, 16 s per thread -> 4 FMA per W-byte
// (L1 no longer the bottleneck). W layout wt4[d][k][j][q] == wiq format.
// ggemm: conflict-free staging (lane=row) + unroll 4.
// Output: d_out[0:32]=score, d_out[32:32+16384]=path (floats).

namespace {

constexpr int T_ = 11;
constexpr int HT = 256 * 512;        // one h slab (j-major, s-innermost)

__device__ __forceinline__ size_t gq_off(int t, int d, int j, int q, int s) {
  return ((((size_t)(t * 2 + d) * 256 + j) * 4 + q) * 512 + s);
}

// ---------------- K0: prep (transposes), flat 1,580,544 elements ----------------
__global__ __launch_bounds__(256) void k_prep(
    const float* __restrict__ w_ih_f, const float* __restrict__ w_ih_b,
    const float* __restrict__ w_hh_f, const float* __restrict__ w_hh_b,
    const float* __restrict__ b_ih_f, const float* __restrict__ b_hh_f,
    const float* __restrict__ b_ih_b, const float* __restrict__ b_hh_b,
    const float* __restrict__ h0, const float* __restrict__ c0,
    const float* __restrict__ w_out,
    float* __restrict__ wiq, float* __restrict__ wt4, float* __restrict__ bq,
    float* __restrict__ ct, float* __restrict__ ht_f, float* __restrict__ ht_b,
    float* __restrict__ wot) {
  const int i = blockIdx.x * 256 + threadIdx.x;
  if (i < 524288) {                                    // wiq from w_ih
    int d = i >> 18, r = i & 262143, gcr = r >> 8, k = r & 255;
    int q = gcr >> 8, j = gcr & 255;
    const float* w = d ? w_ih_b : w_ih_f;
    wiq[((size_t)(d * 256 + k) * 256 + j) * 4 + q] = w[gcr * 256 + k];
  } else if (i < 1048576) {                            // wt4 from w_hh (same fmt)
    int i2 = i - 524288;
    int d = i2 >> 18, r = i2 & 262143, gcr = r >> 8, k = r & 255;
    int q = gcr >> 8, j = gcr & 255;
    const float* w = d ? w_hh_b : w_hh_f;
    wt4[((size_t)(d * 256 + k) * 256 + j) * 4 + q] = w[gcr * 256 + k];
  } else if (i < 1050624) {                            // bq
    int r = i - 1048576;
    int d = r >> 10, x = r & 1023, j = x >> 2, q = x & 3;
    const float* bi = d ? b_ih_b : b_ih_f;
    const float* bh = d ? b_hh_b : b_hh_f;
    bq[r] = bi[q * 256 + j] + bh[q * 256 + j];
  } else if (i < 1312768) {                            // ct from c0
    int r = i - 1050624;
    int d = r >> 17, y = r & 131071, j = y >> 9, s = y & 511;
    ct[r] = c0[((size_t)d * 512 + s) * 256 + j];
  } else if (i < 1574912) {                            // ht slot 0 from h0
    int r = i - 1312768;
    int d = r >> 17, y = r & 131071, j = y >> 9, s = y & 511;
    float v = h0[((size_t)d * 512 + s) * 256 + j];
    if (d == 0) ht_f[y] = v; else ht_b[y] = v;
  } else if (i < 1580544) {                            // wot from w_out
    int r = i - 1574912;
    int k = r / 11, tag = r - k * 11;
    wot[r] = w_out[tag * 512 + k];
  }
}

// ---------------- K1: Gq = x@W_ih^T + bias (embedding fused) ----------------
__global__ __launch_bounds__(256) void k_ggemm(
    const int* __restrict__ sent, const float* __restrict__ embed,
    const float* __restrict__ wiq, const float* __restrict__ bq,
    float* __restrict__ Gq) {
  __shared__ float As[64][67];
  const int tid = threadIdx.x;
  const int bid = blockIdx.x;
  const int jg4 = bid & 15;
  const int d = (bid >> 4) & 1;
  const int rt = bid >> 5;
  const int wid = __builtin_amdgcn_readfirstlane(tid >> 6);
  const int lane = tid & 63;
  const int row0 = rt * 64;
  const int t = row0 >> 9;
  const int sb = (row0 & 511) + lane;
  const int j0 = (jg4 * 4 + wid) * 4;

  // staging: lane = row (conflict-free column writes), wave = k-quad
  const int rr = tid & 63, eq = tid >> 6;
  const int tok = sent[row0 + rr];
  const float* erow = embed + (size_t)tok * 256 + eq * 16;

  float acc[16];
#pragma unroll
  for (int g = 0; g < 16; ++g) acc[g] = 0.f;

  const float* wbase = wiq + (size_t)d * 256 * 1024;

  for (int ci = 0; ci < 4; ++ci) {
    const int k0 = ci * 64;
    const float* ep = erow + k0;
    float4 v0 = *(const float4*)(ep);
    float4 v1 = *(const float4*)(ep + 4);
    float4 v2 = *(const float4*)(ep + 8);
    float4 v3 = *(const float4*)(ep + 12);
    const int kb = eq * 16;
    As[kb + 0][rr] = v0.x;  As[kb + 1][rr] = v0.y;  As[kb + 2][rr] = v0.z;  As[kb + 3][rr] = v0.w;
    As[kb + 4][rr] = v1.x;  As[kb + 5][rr] = v1.y;  As[kb + 6][rr] = v1.z;  As[kb + 7][rr] = v1.w;
    As[kb + 8][rr] = v2.x;  As[kb + 9][rr] = v2.y;  As[kb + 10][rr] = v2.z; As[kb + 11][rr] = v2.w;
    As[kb + 12][rr] = v3.x; As[kb + 13][rr] = v3.y; As[kb + 14][rr] = v3.z; As[kb + 15][rr] = v3.w;
    __syncthreads();
#pragma unroll 4
    for (int kk = 0; kk < 64; ++kk) {
      float a = As[kk][lane];
      const float* wp = wbase + (size_t)(k0 + kk) * 1024 + j0 * 4;  // uniform
#pragma unroll
      for (int g = 0; g < 16; ++g) acc[g] = fmaf(a, wp[g], acc[g]);
    }
    __syncthreads();
  }
  const float* bp = bq + ((size_t)d * 256 + j0) * 4;
#pragma unroll
  for (int g = 0; g < 16; ++g) {
    int jj = g >> 2, q = g & 3;
    Gq[gq_off(t, d, j0 + jj, q, sb)] = acc[g] + bp[g];
  }
}

// ---------------- K2: rstep v3 — lane=(jl,q), 16 s per thread ----------------
// grid 256 = [sg 3][d 1][jsl 4]; 512 thr = (kh 2) x (sq 4) x 64 lanes.
// Per k: W = 1 dword/lane (256B coalesced, L2-resident slice), h = 64B s_load.
__global__ __launch_bounds__(512) void k_rstep(
    const float* __restrict__ wt4, const float* __restrict__ Gq,
    float* __restrict__ ht_f, float* __restrict__ ht_b,
    float* __restrict__ ct, int t) {
  __shared__ float red[256][17];       // kh=1 partials
  __shared__ float gb[4][16][65];      // gates [q][jl][s64]
  const int tid = threadIdx.x;
  const int bid = blockIdx.x;
  const int jsl = bid & 15, d = (bid >> 4) & 1, sg = bid >> 5;
  const int kh = __builtin_amdgcn_readfirstlane(tid >> 8);
  const int sq = __builtin_amdgcn_readfirstlane((tid >> 6) & 3);
  const int rem = tid & 255;
  const int lane = tid & 63;
  const int j0 = jsl * 16;
  const int s0 = sg * 64 + sq * 16;
  const int tt = d ? 31 - t : t;

  float* htX = d ? ht_b : ht_f;
  const float* hprev = htX + (size_t)t * HT;                 // [k 256][s 512]
  const float* wp = wt4 + ((size_t)d * 256 + (size_t)kh * 128) * 1024 + j0 * 4 + lane;
  const float* hp = hprev + (size_t)kh * 128 * 512 + s0;

  float acc[16];
#pragma unroll
  for (int i = 0; i < 16; ++i) acc[i] = 0.f;

#pragma unroll 4
  for (int k = 0; k < 128; ++k) {
    const float w = wp[(size_t)k * 1024];                    // per-lane, coalesced
    const float* h = hp + (size_t)k * 512;                   // wave-uniform
    float4 h0_ = *(const float4*)(h);
    float4 h1_ = *(const float4*)(h + 4);
    float4 h2_ = *(const float4*)(h + 8);
    float4 h3_ = *(const float4*)(h + 12);
    acc[0]  = fmaf(w, h0_.x, acc[0]);
    acc[1]  = fmaf(w, h0_.y, acc[1]);
    acc[2]  = fmaf(w, h0_.z, acc[2]);
    acc[3]  = fmaf(w, h0_.w, acc[3]);
    acc[4]  = fmaf(w, h1_.x, acc[4]);
    acc[5]  = fmaf(w, h1_.y, acc[5]);
    acc[6]  = fmaf(w, h1_.z, acc[6]);
    acc[7]  = fmaf(w, h1_.w, acc[7]);
    acc[8]  = fmaf(w, h2_.x, acc[8]);
    acc[9]  = fmaf(w, h2_.y, acc[9]);
    acc[10] = fmaf(w, h2_.z, acc[10]);
    acc[11] = fmaf(w, h2_.w, acc[11]);
    acc[12] = fmaf(w, h3_.x, acc[12]);
    acc[13] = fmaf(w, h3_.y, acc[13]);
    acc[14] = fmaf(w, h3_.z, acc[14]);
    acc[15] = fmaf(w, h3_.w, acc[15]);
  }

  if (kh == 1) {
#pragma unroll
    for (int i = 0; i < 16; ++i) red[rem][i] = acc[i];
  }
  __syncthreads();
  if (kh == 0) {
    const int jl = lane >> 2, q = lane & 3;
#pragma unroll
    for (int i = 0; i < 16; ++i) gb[q][jl][sq * 16 + i] = acc[i] + red[rem][i];
  }
  __syncthreads();

  // pointwise: 1024 cells (16 j x 64 s), 2 per thread (s-pair)
  {
    const int jl2 = tid >> 5, sp = tid & 31;
    const int j = j0 + jl2;
    const int sloc = sp * 2;
    const int s = sg * 64 + sloc;
    const float* gp = Gq + gq_off(tt, d, j, 0, s);
    float2 gI = *(const float2*)(gp);
    float2 gF = *(const float2*)(gp + 512);
    float2 gG = *(const float2*)(gp + 1024);
    float2 gO = *(const float2*)(gp + 1536);
    const size_t coff = ((size_t)d * 256 + j) * 512 + s;
    float2 c2 = *(const float2*)(ct + coff);
    float giA[2] = {gI.x, gI.y}, gfA[2] = {gF.x, gF.y};
    float ggA[2] = {gG.x, gG.y}, goA[2] = {gO.x, gO.y};
    float cA[2] = {c2.x, c2.y};
    float cnA[2], hA[2];
#pragma unroll
    for (int e = 0; e < 2; ++e) {
      float gi = gb[0][jl2][sloc + e] + giA[e];
      float gf = gb[1][jl2][sloc + e] + gfA[e];
      float gg = gb[2][jl2][sloc + e] + ggA[e];
      float go = gb[3][jl2][sloc + e] + goA[e];
      float si = 1.f / (1.f + expf(-gi));
      float sf = 1.f / (1.f + expf(-gf));
      float tg = tanhf(gg);
      float so = 1.f / (1.f + expf(-go));
      float cn = sf * cA[e] + si * tg;
      cnA[e] = cn;
      hA[e] = so * tanhf(cn);
    }
    *(float2*)(ct + coff) = make_float2(cnA[0], cnA[1]);
    float* ho = htX + (size_t)(t + 1) * HT + (size_t)j * 512 + s;
    *(float2*)ho = make_float2(hA[0], hA[1]);
  }
}

// ---------------- K3: featsT = [hf|hb]@w_out^T + b_out ----------------
__global__ __launch_bounds__(256) void k_out(
    const float* __restrict__ ht_f, const float* __restrict__ ht_b,
    const float* __restrict__ wot, const float* __restrict__ b_out,
    float* __restrict__ featsT) {
  __shared__ float red[4][11][64];
  const int tid = threadIdx.x;
  const int bid = blockIdx.x;
  const int t = bid >> 3, stile = bid & 7;
  const int wid = __builtin_amdgcn_readfirstlane(tid >> 6);
  const int lane = tid & 63;
  const int s0 = stile * 64;
  const int kg0 = wid * 128;
  const float* src = (wid < 2)
      ? ht_f + (size_t)(t + 1) * HT + (size_t)kg0 * 512
      : ht_b + (size_t)(32 - t) * HT + (size_t)(kg0 - 256) * 512;

  float acc[11];
#pragma unroll
  for (int g = 0; g < 11; ++g) acc[g] = 0.f;
#pragma unroll 4
  for (int kk = 0; kk < 128; ++kk) {
    float a = src[(size_t)kk * 512 + s0 + lane];
    const float* wp = wot + (size_t)(kg0 + kk) * 11;
#pragma unroll
    for (int g = 0; g < 11; ++g) acc[g] = fmaf(a, wp[g], acc[g]);
  }
#pragma unroll
  for (int g = 0; g < 11; ++g) red[wid][g][lane] = acc[g];
  __syncthreads();
  if (wid == 0) {
#pragma unroll
    for (int g = 0; g < 11; ++g) {
      float v = red[0][g][lane] + red[1][g][lane] + red[2][g][lane] +
                red[3][g][lane] + b_out[g];
      featsT[(size_t)g * 16384 + t * 512 + s0 + lane] = v;
    }
  }
}

// ---------------- K4: Viterbi ----------------
#define PAIR(va, ia, vb, ib, vo, io) { bool c_ = (va) >= (vb); vo = c_ ? (va) : (vb); io = c_ ? (ia) : (ib); }

__global__ __launch_bounds__(128) void k_viterbi(const float* __restrict__ featsT,
                                                 const float* __restrict__ trans,
                                                 float* __restrict__ out) {
  __shared__ float fl[512 * T_];
  __shared__ unsigned char psiL[511 * T_];
  __shared__ unsigned char specL[121 * 47];
  __shared__ unsigned char selL[16];
  __shared__ int lastL;
  __shared__ float scoreL;
  const int b = blockIdx.x, tid = threadIdx.x;
  for (int i = tid; i < 512 * T_; i += 128) {
    int tag = i >> 9, s = i & 511;
    fl[s * T_ + tag] = featsT[(size_t)tag * 16384 + b * 512 + s];
  }
  __syncthreads();

  if (tid < 64) {
    const int lane = tid;
    const int to = (lane < T_) ? lane : 0;
    float tr[T_];
#pragma unroll
    for (int f = 0; f < T_; ++f) tr[f] = trans[to * T_ + f];
    float delta = (lane == 9) ? 0.f : -10000.f;   // START=9

    for (int s = 1; s < 512; ++s) {
      float v0 = tr[0] + __shfl(delta, 0, 64);
      float v1 = tr[1] + __shfl(delta, 1, 64);
      float v2 = tr[2] + __shfl(delta, 2, 64);
      float v3 = tr[3] + __shfl(delta, 3, 64);
      float v4 = tr[4] + __shfl(delta, 4, 64);
      float v5 = tr[5] + __shfl(delta, 5, 64);
      float v6 = tr[6] + __shfl(delta, 6, 64);
      float v7 = tr[7] + __shfl(delta, 7, 64);
      float v8 = tr[8] + __shfl(delta, 8, 64);
      float v9 = tr[9] + __shfl(delta, 9, 64);
      float v10 = tr[10] + __shfl(delta, 10, 64);
      float mA, mB, mC, mD, mE, mG, mH, mI, mJ, m;
      int iA, iB, iC, iD, iE, iG, iH, iI, iJ, am;
      PAIR(v0, 0, v1, 1, mA, iA); PAIR(v2, 2, v3, 3, mB, iB);
      PAIR(v4, 4, v5, 5, mC, iC); PAIR(v6, 6, v7, 7, mD, iD);
      PAIR(v8, 8, v9, 9, mE, iE);
      PAIR(mA, iA, mB, iB, mG, iG); PAIR(mC, iC, mD, iD, mH, iH);
      PAIR(mE, iE, v10, 10, mI, iI);
      PAIR(mG, iG, mH, iH, mJ, iJ);
      PAIR(mJ, iJ, mI, iI, m, am);
      if (lane < T_) psiL[(s - 1) * T_ + lane] = (unsigned char)am;
      delta = m + fl[s * T_ + to];
    }
    float d0 = __shfl(delta, 0, 64), d1 = __shfl(delta, 1, 64);
    float d2 = __shfl(delta, 2, 64), d3 = __shfl(delta, 3, 64);
    float d4 = __shfl(delta, 4, 64), d5 = __shfl(delta, 5, 64);
    float d6 = __shfl(delta, 6, 64), d7 = __shfl(delta, 7, 64);
    float d8 = __shfl(delta, 8, 64), d9 = __shfl(delta, 9, 64);
    float d10 = __shfl(delta, 10, 64);
    float mA, mB, mC, mD, mE, mG, mH, mI, mJ, m;
    int iA, iB, iC, iD, iE, iG, iH, iI, iJ, am;
    PAIR(d0, 0, d1, 1, mA, iA); PAIR(d2, 2, d3, 3, mB, iB);
    PAIR(d4, 4, d5, 5, mC, iC); PAIR(d6, 6, d7, 7, mD, iD);
    PAIR(d8, 8, d9, 9, mE, iE);
    PAIR(mA, iA, mB, iB, mG, iG); PAIR(mC, iC, mD, iD, mH, iH);
    PAIR(mE, iE, d10, 10, mI, iI);
    PAIR(mG, iG, mH, iH, mJ, iJ);
    PAIR(mJ, iJ, mI, iI, m, am);
    if (lane == 0) { lastL = am; scoreL = m; }
  }
  __syncthreads();

  const int last = lastL;
  if (tid < 121) {
    const int g = tid / 11, tau = tid - g * 11;
    const int khi = 510 - 47 * g;
    const int len = (g < 10) ? 47 : 41;
    int cur = tau;
    unsigned char* sp = &specL[(g * 11 + tau) * 47];
    for (int i = 0; i < len; ++i) {
      cur = psiL[(khi - i) * T_ + cur];
      sp[i] = (unsigned char)cur;
    }
  }
  __syncthreads();
  if (tid == 0) {
    int cur = last;
    for (int g = 0; g < 11; ++g) {
      selL[g] = (unsigned char)cur;
      int len = (g < 10) ? 47 : 41;
      cur = specL[(g * 11 + cur) * 47 + (len - 1)];
    }
    out[b] = scoreL;
    out[32 + (size_t)b * 512 + 511] = (float)last;
  }
  __syncthreads();
  if (tid < 121) {
    const int g = tid / 11, tau = tid - g * 11;
    if (tau == selL[g]) {
      const int khi = 510 - 47 * g;
      const int len = (g < 10) ? 47 : 41;
      float* path = out + 32 + (size_t)b * 512;
      const unsigned char* sp = &specL[(g * 11 + tau) * 47];
      for (int i = 0; i < len; ++i) path[khi - i] = (float)sp[i];
    }
  }
}

}  // namespace

extern "C" void kernel_launch(void* const* d_in, const int* in_sizes, int n_in,
                              void* d_out, int out_size, void* d_ws, size_t ws_size,
                              hipStream_t stream) {
  const int* sent     = (const int*)d_in[0];
  const float* embed  = (const float*)d_in[1];
  const float* w_ih_f = (const float*)d_in[2];
  const float* w_hh_f = (const float*)d_in[3];
  const float* b_ih_f = (const float*)d_in[4];
  const float* b_hh_f = (const float*)d_in[5];
  const float* w_ih_b = (const float*)d_in[6];
  const float* w_hh_b = (const float*)d_in[7];
  const float* b_ih_b = (const float*)d_in[8];
  const float* b_hh_b = (const float*)d_in[9];
  const float* h0     = (const float*)d_in[10];
  const float* c0     = (const float*)d_in[11];
  const float* w_out  = (const float*)d_in[12];
  const float* b_out  = (const float*)d_in[13];
  const float* trans  = (const float*)d_in[14];

  float* ws = (float*)d_ws;
  float* Gq     = ws;                      // 33,554,432
  float* ht_f   = Gq + 33554432;           //  4,325,376  (33 slabs)
  float* ht_b   = ht_f + 4325376;          //  4,325,376
  float* ct     = ht_b + 4325376;          //    262,144
  float* wiq    = ct + 262144;             //    524,288
  float* wt4    = wiq + 524288;            //    524,288
  float* bq     = wt4 + 524288;            //      2,048
  float* wot    = bq + 2048;               //      5,632
  float* featsT = wot + 5632;              //    180,224
  // total 43,703,808 floats = 166.7 MiB

  k_prep<<<6174, 256, 0, stream>>>(w_ih_f, w_ih_b, w_hh_f, w_hh_b,
                                   b_ih_f, b_hh_f, b_ih_b, b_hh_b,
                                   h0, c0, w_out,
                                   wiq, wt4, bq, ct, ht_f, ht_b, wot);
  k_ggemm<<<8192, 256, 0, stream>>>(sent, embed, wiq, bq, Gq);
  for (int t = 0; t < 32; ++t)
    k_rstep<<<256, 512, 0, stream>>>(wt4, Gq, ht_f, ht_b, ct, t);
  k_out<<<256, 256, 0, stream>>>(ht_f, ht_b, wot, b_out, featsT);
  k_viterbi<<<32, 128, 0, stream>>>(featsT, trans, (float*)d_out);
}

// Round 10
// 799.767 us; speedup vs baseline: 3.0063x; 1.0212x over previous
//
#include <hip/hip_runtime.h>
#include <math.h>

// BiLSTM-CRF fp32, round 10.
// rstep v4: same lane=(jl,q)/16-s dataflow, but grid 512 x block 512 =
//   (kh 4 x sq 2 x 64), s-tile 32 -> 4 waves/SIMD (2x occupancy).
// ggemm v3: wave owns 8j x 4q (acc[32]) -> 32 FMA per LDS-read+s_load.
// viterbi v3: max-only critical path (v_max3 tree), argmax via ==/ffs off-path.
// Output: d_out[0:32]=score, d_out[32:32+16384]=path (floats).

namespace {

constexpr int T_ = 11;
constexpr int HT = 256 * 512;        // one h slab (j-major, s-innermost)

__device__ __forceinline__ size_t gq_off(int t, int d, int j, int q, int s) {
  return ((((size_t)(t * 2 + d) * 256 + j) * 4 + q) * 512 + s);
}

// ---------------- K0: prep (transposes), flat 1,580,544 elements ----------------
__global__ __launch_bounds__(256) void k_prep(
    const float* __restrict__ w_ih_f, const float* __restrict__ w_ih_b,
    const float* __restrict__ w_hh_f, const float* __restrict__ w_hh_b,
    const float* __restrict__ b_ih_f, const float* __restrict__ b_hh_f,
    const float* __restrict__ b_ih_b, const float* __restrict__ b_hh_b,
    const float* __restrict__ h0, const float* __restrict__ c0,
    const float* __restrict__ w_out,
    float* __restrict__ wiq, float* __restrict__ wt4, float* __restrict__ bq,
    float* __restrict__ ct, float* __restrict__ ht_f, float* __restrict__ ht_b,
    float* __restrict__ wot) {
  const int i = blockIdx.x * 256 + threadIdx.x;
  if (i < 524288) {                                    // wiq from w_ih
    int d = i >> 18, r = i & 262143, gcr = r >> 8, k = r & 255;
    int q = gcr >> 8, j = gcr & 255;
    const float* w = d ? w_ih_b : w_ih_f;
    wiq[((size_t)(d * 256 + k) * 256 + j) * 4 + q] = w[gcr * 256 + k];
  } else if (i < 1048576) {                            // wt4 from w_hh (same fmt)
    int i2 = i - 524288;
    int d = i2 >> 18, r = i2 & 262143, gcr = r >> 8, k = r & 255;
    int q = gcr >> 8, j = gcr & 255;
    const float* w = d ? w_hh_b : w_hh_f;
    wt4[((size_t)(d * 256 + k) * 256 + j) * 4 + q] = w[gcr * 256 + k];
  } else if (i < 1050624) {                            // bq
    int r = i - 1048576;
    int d = r >> 10, x = r & 1023, j = x >> 2, q = x & 3;
    const float* bi = d ? b_ih_b : b_ih_f;
    const float* bh = d ? b_hh_b : b_hh_f;
    bq[r] = bi[q * 256 + j] + bh[q * 256 + j];
  } else if (i < 1312768) {                            // ct from c0
    int r = i - 1050624;
    int d = r >> 17, y = r & 131071, j = y >> 9, s = y & 511;
    ct[r] = c0[((size_t)d * 512 + s) * 256 + j];
  } else if (i < 1574912) {                            // ht slot 0 from h0
    int r = i - 1312768;
    int d = r >> 17, y = r & 131071, j = y >> 9, s = y & 511;
    float v = h0[((size_t)d * 512 + s) * 256 + j];
    if (d == 0) ht_f[y] = v; else ht_b[y] = v;
  } else if (i < 1580544) {                            // wot from w_out
    int r = i - 1574912;
    int k = r / 11, tag = r - k * 11;
    wot[r] = w_out[tag * 512 + k];
  }
}

// ---------------- K1: Gq = x@W_ih^T + bias (embedding fused) ----------------
// grid 4096 = [rt 256][d 2][jg8 8]; 256 thr = 4 waves; wave: 64 rows x 32 gc
// (8 j x 4 q). lane = row. A via LDS; W via wave-uniform s_load (128 B/kk).
__global__ __launch_bounds__(256, 4) void k_ggemm(
    const int* __restrict__ sent, const float* __restrict__ embed,
    const float* __restrict__ wiq, const float* __restrict__ bq,
    float* __restrict__ Gq) {
  __shared__ float As[64][67];
  const int tid = threadIdx.x;
  const int bid = blockIdx.x;
  const int jg8 = bid & 7;
  const int d = (bid >> 3) & 1;
  const int rt = bid >> 4;
  const int wid = __builtin_amdgcn_readfirstlane(tid >> 6);
  const int lane = tid & 63;
  const int row0 = rt * 64;
  const int t = row0 >> 9;
  const int sb = (row0 & 511) + lane;
  const int j0 = (jg8 * 4 + wid) * 8;      // 8 j per wave

  // staging: lane = row (conflict-free), wave = k-quad
  const int rr = tid & 63, eq = tid >> 6;
  const int tok = sent[row0 + rr];
  const float* erow = embed + (size_t)tok * 256 + eq * 16;

  float acc[32];
#pragma unroll
  for (int g = 0; g < 32; ++g) acc[g] = 0.f;

  const float* wbase = wiq + (size_t)d * 256 * 1024;

  for (int ci = 0; ci < 4; ++ci) {
    const int k0 = ci * 64;
    const float* ep = erow + k0;
    float4 v0 = *(const float4*)(ep);
    float4 v1 = *(const float4*)(ep + 4);
    float4 v2 = *(const float4*)(ep + 8);
    float4 v3 = *(const float4*)(ep + 12);
    const int kb = eq * 16;
    As[kb + 0][rr] = v0.x;  As[kb + 1][rr] = v0.y;  As[kb + 2][rr] = v0.z;  As[kb + 3][rr] = v0.w;
    As[kb + 4][rr] = v1.x;  As[kb + 5][rr] = v1.y;  As[kb + 6][rr] = v1.z;  As[kb + 7][rr] = v1.w;
    As[kb + 8][rr] = v2.x;  As[kb + 9][rr] = v2.y;  As[kb + 10][rr] = v2.z; As[kb + 11][rr] = v2.w;
    As[kb + 12][rr] = v3.x; As[kb + 13][rr] = v3.y; As[kb + 14][rr] = v3.z; As[kb + 15][rr] = v3.w;
    __syncthreads();
#pragma unroll 2
    for (int kk = 0; kk < 64; ++kk) {
      float a = As[kk][lane];
      const float* wp = wbase + (size_t)(k0 + kk) * 1024 + j0 * 4;  // uniform
#pragma unroll
      for (int g = 0; g < 32; ++g) acc[g] = fmaf(a, wp[g], acc[g]);
    }
    __syncthreads();
  }
  const float* bp = bq + ((size_t)d * 256 + j0) * 4;
#pragma unroll
  for (int g = 0; g < 32; ++g) {
    int jj = g >> 2, q = g & 3;
    Gq[gq_off(t, d, j0 + jj, q, sb)] = acc[g] + bp[g];
  }
}

// ---------------- K2: rstep v4 — lane=(jl,q), 16 s/thread, 4 waves/SIMD ----------------
// grid 512 = [sg 16][d 2][jsl 16]; block 512 = (kh 4) x (sq 2) x 64 lanes.
// Per k: W = 1 dword/lane (256B coalesced, L2-resident), h = 64B uniform s_load.
__global__ __launch_bounds__(512, 4) void k_rstep(
    const float* __restrict__ wt4, const float* __restrict__ Gq,
    float* __restrict__ ht_f, float* __restrict__ ht_b,
    float* __restrict__ ct, int t) {
  __shared__ float red[3][128][17];    // kh=1..3 partials
  __shared__ float gb[4][16][33];      // gates [q][jl][s32]
  const int tid = threadIdx.x;
  const int bid = blockIdx.x;
  const int jsl = bid & 15, d = (bid >> 4) & 1, sg = bid >> 5;   // sg 0..15
  const int kh = __builtin_amdgcn_readfirstlane(tid >> 7);       // 0..3
  const int sq = __builtin_amdgcn_readfirstlane((tid >> 6) & 1); // 0..1
  const int rem = tid & 127;
  const int lane = tid & 63;
  const int j0 = jsl * 16;
  const int s0 = sg * 32 + sq * 16;
  const int tt = d ? 31 - t : t;

  float* htX = d ? ht_b : ht_f;
  const float* hprev = htX + (size_t)t * HT;                 // [k 256][s 512]
  const float* wp = wt4 + ((size_t)d * 256 + (size_t)kh * 64) * 1024 + j0 * 4 + lane;
  const float* hp = hprev + (size_t)kh * 64 * 512 + s0;

  float acc[16];
#pragma unroll
  for (int i = 0; i < 16; ++i) acc[i] = 0.f;

#pragma unroll 4
  for (int k = 0; k < 64; ++k) {
    const float w = wp[(size_t)k * 1024];                    // per-lane, coalesced
    const float* h = hp + (size_t)k * 512;                   // wave-uniform
    float4 h0_ = *(const float4*)(h);
    float4 h1_ = *(const float4*)(h + 4);
    float4 h2_ = *(const float4*)(h + 8);
    float4 h3_ = *(const float4*)(h + 12);
    acc[0]  = fmaf(w, h0_.x, acc[0]);
    acc[1]  = fmaf(w, h0_.y, acc[1]);
    acc[2]  = fmaf(w, h0_.z, acc[2]);
    acc[3]  = fmaf(w, h0_.w, acc[3]);
    acc[4]  = fmaf(w, h1_.x, acc[4]);
    acc[5]  = fmaf(w, h1_.y, acc[5]);
    acc[6]  = fmaf(w, h1_.z, acc[6]);
    acc[7]  = fmaf(w, h1_.w, acc[7]);
    acc[8]  = fmaf(w, h2_.x, acc[8]);
    acc[9]  = fmaf(w, h2_.y, acc[9]);
    acc[10] = fmaf(w, h2_.z, acc[10]);
    acc[11] = fmaf(w, h2_.w, acc[11]);
    acc[12] = fmaf(w, h3_.x, acc[12]);
    acc[13] = fmaf(w, h3_.y, acc[13]);
    acc[14] = fmaf(w, h3_.z, acc[14]);
    acc[15] = fmaf(w, h3_.w, acc[15]);
  }

  if (kh > 0) {
#pragma unroll
    for (int i = 0; i < 16; ++i) red[kh - 1][rem][i] = acc[i];
  }
  __syncthreads();
  if (kh == 0) {
    const int jl = lane >> 2, q = lane & 3;
#pragma unroll
    for (int i = 0; i < 16; ++i) {
      float v = acc[i] + red[0][rem][i] + red[1][rem][i] + red[2][rem][i];
      gb[q][jl][sq * 16 + i] = v;
    }
  }
  __syncthreads();

  // pointwise: 512 cells (16 j x 32 s), 1 per thread
  {
    const int jl2 = tid >> 5, sp = tid & 31;
    const int j = j0 + jl2;
    const int s = sg * 32 + sp;
    const float* gp = Gq + gq_off(tt, d, j, 0, s);
    float gi = gb[0][jl2][sp] + gp[0];
    float gf = gb[1][jl2][sp] + gp[512];
    float gg = gb[2][jl2][sp] + gp[1024];
    float go = gb[3][jl2][sp] + gp[1536];
    float si = 1.f / (1.f + expf(-gi));
    float sf = 1.f / (1.f + expf(-gf));
    float tg = tanhf(gg);
    float so = 1.f / (1.f + expf(-go));
    const size_t coff = ((size_t)d * 256 + j) * 512 + s;
    float cp = ct[coff];
    float cn = sf * cp + si * tg;
    float hn = so * tanhf(cn);
    ct[coff] = cn;
    htX[(size_t)(t + 1) * HT + (size_t)j * 512 + s] = hn;
  }
}

// ---------------- K3: featsT = [hf|hb]@w_out^T + b_out ----------------
__global__ __launch_bounds__(256) void k_out(
    const float* __restrict__ ht_f, const float* __restrict__ ht_b,
    const float* __restrict__ wot, const float* __restrict__ b_out,
    float* __restrict__ featsT) {
  __shared__ float red[4][11][64];
  const int tid = threadIdx.x;
  const int bid = blockIdx.x;
  const int t = bid >> 3, stile = bid & 7;
  const int wid = __builtin_amdgcn_readfirstlane(tid >> 6);
  const int lane = tid & 63;
  const int s0 = stile * 64;
  const int kg0 = wid * 128;
  const float* src = (wid < 2)
      ? ht_f + (size_t)(t + 1) * HT + (size_t)kg0 * 512
      : ht_b + (size_t)(32 - t) * HT + (size_t)(kg0 - 256) * 512;

  float acc[11];
#pragma unroll
  for (int g = 0; g < 11; ++g) acc[g] = 0.f;
#pragma unroll 4
  for (int kk = 0; kk < 128; ++kk) {
    float a = src[(size_t)kk * 512 + s0 + lane];
    const float* wp = wot + (size_t)(kg0 + kk) * 11;
#pragma unroll
    for (int g = 0; g < 11; ++g) acc[g] = fmaf(a, wp[g], acc[g]);
  }
#pragma unroll
  for (int g = 0; g < 11; ++g) red[wid][g][lane] = acc[g];
  __syncthreads();
  if (wid == 0) {
#pragma unroll
    for (int g = 0; g < 11; ++g) {
      float v = red[0][g][lane] + red[1][g][lane] + red[2][g][lane] +
                red[3][g][lane] + b_out[g];
      featsT[(size_t)g * 16384 + t * 512 + s0 + lane] = v;
    }
  }
}

// ---------------- K4: Viterbi v3 — max3 critical path, argmax off-path ----------------
__global__ __launch_bounds__(128) void k_viterbi(const float* __restrict__ featsT,
                                                 const float* __restrict__ trans,
                                                 float* __restrict__ out) {
  __shared__ float fl[512 * T_];
  __shared__ unsigned char psiL[511 * T_];
  __shared__ unsigned char specL[121 * 47];
  __shared__ unsigned char selL[16];
  __shared__ int lastL;
  __shared__ float scoreL;
  const int b = blockIdx.x, tid = threadIdx.x;
  for (int i = tid; i < 512 * T_; i += 128) {
    int tag = i >> 9, s = i & 511;
    fl[s * T_ + tag] = featsT[(size_t)tag * 16384 + b * 512 + s];
  }
  __syncthreads();

  if (tid < 64) {
    const int lane = tid;
    const int to = (lane < T_) ? lane : 0;
    float tr[T_];
#pragma unroll
    for (int f = 0; f < T_; ++f) tr[f] = trans[to * T_ + f];
    float delta = (lane == 9) ? 0.f : -10000.f;   // START=9

    for (int s = 1; s < 512; ++s) {
      float fv = fl[s * T_ + to];               // independent: issues early
      float v0 = tr[0] + __shfl(delta, 0, 64);
      float v1 = tr[1] + __shfl(delta, 1, 64);
      float v2 = tr[2] + __shfl(delta, 2, 64);
      float v3 = tr[3] + __shfl(delta, 3, 64);
      float v4 = tr[4] + __shfl(delta, 4, 64);
      float v5 = tr[5] + __shfl(delta, 5, 64);
      float v6 = tr[6] + __shfl(delta, 6, 64);
      float v7 = tr[7] + __shfl(delta, 7, 64);
      float v8 = tr[8] + __shfl(delta, 8, 64);
      float v9 = tr[9] + __shfl(delta, 9, 64);
      float v10 = tr[10] + __shfl(delta, 10, 64);
      // critical path: pure max tree (v_max3-friendly)
      float mA = fmaxf(fmaxf(v0, v1), v2);
      float mB = fmaxf(fmaxf(v3, v4), v5);
      float mC = fmaxf(fmaxf(v6, v7), v8);
      float mD = fmaxf(v9, v10);
      float m = fmaxf(fmaxf(mA, mB), fmaxf(mC, mD));
      delta = m + fv;
      // off critical path: first-max index (== jnp.argmax)
      unsigned msk = (v0 == m) ? 1u : 0u;
      msk |= (v1 == m) ? 2u : 0u;
      msk |= (v2 == m) ? 4u : 0u;
      msk |= (v3 == m) ? 8u : 0u;
      msk |= (v4 == m) ? 16u : 0u;
      msk |= (v5 == m) ? 32u : 0u;
      msk |= (v6 == m) ? 64u : 0u;
      msk |= (v7 == m) ? 128u : 0u;
      msk |= (v8 == m) ? 256u : 0u;
      msk |= (v9 == m) ? 512u : 0u;
      msk |= (v10 == m) ? 1024u : 0u;
      int am = __ffs(msk) - 1;
      if (lane < T_) psiL[(s - 1) * T_ + lane] = (unsigned char)am;
    }
    // score + last tag (uniform across lanes)
    float d0 = __shfl(delta, 0, 64), d1 = __shfl(delta, 1, 64);
    float d2 = __shfl(delta, 2, 64), d3 = __shfl(delta, 3, 64);
    float d4 = __shfl(delta, 4, 64), d5 = __shfl(delta, 5, 64);
    float d6 = __shfl(delta, 6, 64), d7 = __shfl(delta, 7, 64);
    float d8 = __shfl(delta, 8, 64), d9 = __shfl(delta, 9, 64);
    float d10 = __shfl(delta, 10, 64);
    float mA = fmaxf(fmaxf(d0, d1), d2);
    float mB = fmaxf(fmaxf(d3, d4), d5);
    float mC = fmaxf(fmaxf(d6, d7), d8);
    float mD = fmaxf(d9, d10);
    float m = fmaxf(fmaxf(mA, mB), fmaxf(mC, mD));
    unsigned msk = (d0 == m) ? 1u : 0u;
    msk |= (d1 == m) ? 2u : 0u;
    msk |= (d2 == m) ? 4u : 0u;
    msk |= (d3 == m) ? 8u : 0u;
    msk |= (d4 == m) ? 16u : 0u;
    msk |= (d5 == m) ? 32u : 0u;
    msk |= (d6 == m) ? 64u : 0u;
    msk |= (d7 == m) ? 128u : 0u;
    msk |= (d8 == m) ? 256u : 0u;
    msk |= (d9 == m) ? 512u : 0u;
    msk |= (d10 == m) ? 1024u : 0u;
    int am = __ffs(msk) - 1;
    if (lane == 0) { lastL = am; scoreL = m; }
  }
  __syncthreads();

  const int last = lastL;
  if (tid < 121) {
    const int g = tid / 11, tau = tid - g * 11;
    const int khi = 510 - 47 * g;
    const int len = (g < 10) ? 47 : 41;
    int cur = tau;
    unsigned char* sp = &specL[(g * 11 + tau) * 47];
    for (int i = 0; i < len; ++i) {
      cur = psiL[(khi - i) * T_ + cur];
      sp[i] = (unsigned char)cur;
    }
  }
  __syncthreads();
  if (tid == 0) {
    int cur = last;
    for (int g = 0; g < 11; ++g) {
      selL[g] = (unsigned char)cur;
      int len = (g < 10) ? 47 : 41;
      cur = specL[(g * 11 + cur) * 47 + (len - 1)];
    }
    out[b] = scoreL;
    out[32 + (size_t)b * 512 + 511] = (float)last;
  }
  __syncthreads();
  if (tid < 121) {
    const int g = tid / 11, tau = tid - g * 11;
    if (tau == selL[g]) {
      const int khi = 510 - 47 * g;
      const int len = (g < 10) ? 47 : 41;
      float* path = out + 32 + (size_t)b * 512;
      const unsigned char* sp = &specL[(g * 11 + tau) * 47];
      for (int i = 0; i < len; ++i) path[khi - i] = (float)sp[i];
    }
  }
}

}  // namespace

extern "C" void kernel_launch(void* const* d_in, const int* in_sizes, int n_in,
                              void* d_out, int out_size, void* d_ws, size_t ws_size,
                              hipStream_t stream) {
  const int* sent     = (const int*)d_in[0];
  const float* embed  = (const float*)d_in[1];
  const float* w_ih_f = (const float*)d_in[2];
  const float* w_hh_f = (const float*)d_in[3];
  const float* b_ih_f = (const float*)d_in[4];
  const float* b_hh_f = (const float*)d_in[5];
  const float* w_ih_b = (const float*)d_in[6];
  const float* w_hh_b = (const float*)d_in[7];
  const float* b_ih_b = (const float*)d_in[8];
  const float* b_hh_b = (const float*)d_in[9];
  const float* h0     = (const float*)d_in[10];
  const float* c0     = (const float*)d_in[11];
  const float* w_out  = (const float*)d_in[12];
  const float* b_out  = (const float*)d_in[13];
  const float* trans  = (const float*)d_in[14];

  float* ws = (float*)d_ws;
  float* Gq     = ws;                      // 33,554,432
  float* ht_f   = Gq + 33554432;           //  4,325,376  (33 slabs)
  float* ht_b   = ht_f + 4325376;          //  4,325,376
  float* ct     = ht_b + 4325376;          //    262,144
  float* wiq    = ct + 262144;             //    524,288
  float* wt4    = wiq + 524288;            //    524,288
  float* bq     = wt4 + 524288;            //      2,048
  float* wot    = bq + 2048;               //      5,632
  float* featsT = wot + 5632;              //    180,224
  // total 43,703,808 floats = 166.7 MiB

  k_prep<<<6174, 256, 0, stream>>>(w_ih_f, w_ih_b, w_hh_f, w_hh_b,
                                   b_ih_f, b_hh_f, b_ih_b, b_hh_b,
                                   h0, c0, w_out,
                                   wiq, wt4, bq, ct, ht_f, ht_b, wot);
  k_ggemm<<<4096, 256, 0, stream>>>(sent, embed, wiq, bq, Gq);
  for (int t = 0; t < 32; ++t)
    k_rstep<<<512, 512, 0, stream>>>(wt4, Gq, ht_f, ht_b, ct, t);
  k_out<<<256, 256, 0, stream>>>(ht_f, ht_b, wot, b_out, featsT);
  k_viterbi<<<32, 128, 0, stream>>>(featsT, trans, (float*)d_out);
}